// Round 10
// baseline (678.906 us; speedup 1.0000x reference)
//
#include <hip/hip_runtime.h>

#define NN 512
#define BSZ 64
#define TTOT 200
#define NSTEP 199
#define DD 32

typedef __attribute__((ext_vector_type(8))) short bf16x8;
typedef __attribute__((ext_vector_type(8))) int i32x8;
typedef __attribute__((ext_vector_type(4))) float f32x4;
typedef __attribute__((ext_vector_type(4))) unsigned int u32x4;

__device__ __forceinline__ float bf2f(unsigned short u) {
  union { unsigned int i; float f; } v; v.i = ((unsigned int)u) << 16; return v.f;
}
__device__ __forceinline__ unsigned short f2bf(float f) {  // RNE
  unsigned int b = __float_as_uint(f);
  return (unsigned short)((b + 0x7fffu + ((b >> 16) & 1u)) >> 16);
}
__device__ __forceinline__ unsigned int pk_trunc(float hi, float lo) {
  return __builtin_amdgcn_perm(__float_as_uint(hi), __float_as_uint(lo), 0x07060302u);
}
// f32 -> OCP e4m3 (RNE on normals; flush tiny to 0; clamp 448)
__device__ __forceinline__ unsigned char e4m3(float x) {
  float a = fabsf(x);
  unsigned int s = (__float_as_uint(x) >> 24) & 0x80u;
  if (a < 0.01171875f) return (unsigned char)s;
  a = fminf(a, 448.0f);
  unsigned int u = __float_as_uint(a);
  unsigned int keep = (u >> 20) & 7u;
  unsigned int rest = u & 0xFFFFFu;
  unsigned int base = (((u >> 23) - 120u) << 3) | keep;
  unsigned int rnd = (rest > 0x80000u) || (rest == 0x80000u && (keep & 1u));
  return (unsigned char)(s | (base + rnd));
}
__device__ __forceinline__ float dec8(unsigned char x) {  // e4m3 -> f32
  int e = (x >> 3) & 15, m = x & 7;
  float v = e ? ldexpf(8.f + (float)m, e - 10) : ldexpf((float)m, -9);
  return (x & 0x80) ? -v : v;
}
__device__ __forceinline__ float rlane(float v, int l) {
  return __int_as_float(__builtin_amdgcn_readlane(__float_as_int(v), l));
}

// K=32 fp8 B-frag layout (round-4 HW-PROVEN)
__device__ __forceinline__ size_t m8_addr(int k, int col) {
  int nt = col >> 4, cch = k >> 5;
  int l2 = (((k >> 3) & 3) << 4) + (col & 15);
  return (size_t)((nt * 16 + cch) * 512) + (size_t)l2 * 8 + (size_t)(k & 7);
}
// K=128 MX B-frag layout (probe-verified)
__device__ __forceinline__ size_t m8mxa(int k, int col) {
  int f = ((k >> 7) << 5) + (col >> 4);
  int ln2 = (((k >> 5) & 3) << 4) + (col & 15);
  return (((size_t)f * 64 + ln2) << 5) + (size_t)(k & 31);
}

// ---------------------------------------------------------------------------
// Transpose+convert: A1 (f32 [b][r][c]) -> A1T (bf16 [b][c][r]).
// ---------------------------------------------------------------------------
__global__ __launch_bounds__(256) void transpose_kernel(
    const float* __restrict__ A1, unsigned short* __restrict__ A1T) {
  const int b = blockIdx.z, ct = blockIdx.x * 64, rt = blockIdx.y * 64;
  const int t = threadIdx.x;
  __shared__ unsigned int tl[64][33];
  {
    const int rp = t >> 3, cs = (t & 7) * 8;
    const float* p0 = A1 + (size_t)b * NN * NN + (size_t)(rt + 2 * rp) * NN + ct + cs;
    f32x4 a0 = *(const f32x4*)p0, a1 = *(const f32x4*)(p0 + 4);
    f32x4 b0 = *(const f32x4*)(p0 + NN), b1 = *(const f32x4*)(p0 + NN + 4);
#pragma unroll
    for (int j = 0; j < 4; ++j) {
      tl[cs + j][rp] = pk_trunc(b0[j], a0[j]);
      tl[cs + 4 + j][rp] = pk_trunc(b1[j], a1[j]);
    }
  }
  __syncthreads();
  {
    const int c = t >> 2, rps = (t & 3) * 8;
    unsigned int v[8];
#pragma unroll
    for (int j = 0; j < 8; ++j) v[j] = tl[c][rps + j];
    unsigned int* dst = (unsigned int*)(A1T + (size_t)b * NN * NN +
                                        (size_t)(ct + c) * NN + rt) + rps;
    *(u32x4*)dst = u32x4{v[0], v[1], v[2], v[3]};
    *(u32x4*)(dst + 4) = u32x4{v[4], v[5], v[6], v[7]};
  }
}

// ---------------------------------------------------------------------------
// GEMM 1 fast (LDS-staged): A2 = A1@A1, bf16 out.  128x128 tile, BK=64,
// 4 waves (2x2).  Bit-identical MFMA sequence to the proven direct version.
// ---------------------------------------------------------------------------
__global__ __launch_bounds__(256) void gemm_a2_fast(
    const float* __restrict__ A1, const unsigned short* __restrict__ A1T,
    unsigned short* __restrict__ A2) {
  const int tn = blockIdx.x, tm = blockIdx.y, b = blockIdx.z;
  const int tid = threadIdx.x, lane = tid & 63;
  const int w = tid >> 6, wr = w >> 1, wc = w & 1;
  const int q = lane >> 4, ln = lane & 15;
  const size_t Ao = (size_t)b * NN * NN;
  __shared__ __align__(16) unsigned char Asw[128 * 128];
  __shared__ __align__(16) unsigned char Bsw[128 * 128];
  f32x4 acc[4][4];
#pragma unroll
  for (int mi = 0; mi < 4; ++mi)
#pragma unroll
    for (int ni = 0; ni < 4; ++ni) acc[mi][ni] = f32x4{0.f, 0.f, 0.f, 0.f};

  const int arow = tid >> 2, achk = tid & 3;
  const int brow = tid >> 1, bh = tid & 1;
  const float* Ab = A1 + Ao;
  const unsigned short* Bb = A1T + Ao;

  for (int k0 = 0; k0 < NN; k0 += 64) {
#pragma unroll
    for (int p = 0; p < 2; ++p) {
      const int r = arow + p * 64;
      const float* src = Ab + (size_t)(tm * 128 + r) * NN + k0 + achk * 16;
      f32x4 x0 = *(const f32x4*)src, x1 = *(const f32x4*)(src + 4);
      f32x4 x2 = *(const f32x4*)(src + 8), x3 = *(const f32x4*)(src + 12);
      u32x4 y0 = u32x4{pk_trunc(x0[1], x0[0]), pk_trunc(x0[3], x0[2]),
                       pk_trunc(x1[1], x1[0]), pk_trunc(x1[3], x1[2])};
      u32x4 y1 = u32x4{pk_trunc(x2[1], x2[0]), pk_trunc(x2[3], x2[2]),
                       pk_trunc(x3[1], x3[0]), pk_trunc(x3[3], x3[2])};
      const int sw = r & 7;
      *(u32x4*)(Asw + r * 128 + (((achk * 2) ^ sw) << 4)) = y0;
      *(u32x4*)(Asw + r * 128 + (((achk * 2 + 1) ^ sw) << 4)) = y1;
    }
    {
      const unsigned short* src = Bb + (size_t)(tn * 128 + brow) * NN + k0 + bh * 32;
      const int sw = brow & 7;
#pragma unroll
      for (int j = 0; j < 4; ++j) {
        u32x4 v = *(const u32x4*)(src + j * 8);
        *(u32x4*)(Bsw + brow * 128 + (((bh * 4 + j) ^ sw) << 4)) = v;
      }
    }
    __syncthreads();
#pragma unroll
    for (int ks = 0; ks < 2; ++ks) {
      bf16x8 af[4], bv[4];
#pragma unroll
      for (int mi = 0; mi < 4; ++mi) {
        const int r = wr * 64 + mi * 16 + ln;
        af[mi] = *(const bf16x8*)(Asw + r * 128 + (((ks * 4 + q) ^ (r & 7)) << 4));
      }
#pragma unroll
      for (int ni = 0; ni < 4; ++ni) {
        const int r = wc * 64 + ni * 16 + ln;
        bv[ni] = *(const bf16x8*)(Bsw + r * 128 + (((ks * 4 + q) ^ (r & 7)) << 4));
      }
#pragma unroll
      for (int mi = 0; mi < 4; ++mi)
#pragma unroll
        for (int ni = 0; ni < 4; ++ni)
          acc[mi][ni] = __builtin_amdgcn_mfma_f32_16x16x32_bf16(
              af[mi], bv[ni], acc[mi][ni], 0, 0, 0);
    }
    __syncthreads();
  }
  unsigned short* Cb = A2 + Ao;
#pragma unroll
  for (int mi = 0; mi < 4; ++mi)
#pragma unroll
    for (int ni = 0; ni < 4; ++ni) {
      const int col = tn * 128 + wc * 64 + ni * 16 + ln;
#pragma unroll
      for (int r = 0; r < 4; ++r) {
        const int row = tm * 128 + wr * 64 + mi * 16 + q * 4 + r;
        Cb[(size_t)row * NN + col] = f2bf(acc[mi][ni][r]);
      }
    }
}

// ---------------------------------------------------------------------------
// GEMM 2 fast (LDS-staged): A3 = A2@A1; M*2^20 -> e4m3 dual layouts.
// ---------------------------------------------------------------------------
__global__ __launch_bounds__(256) void gemm_m_fast(
    const float* __restrict__ A1, const unsigned short* __restrict__ A1T,
    const unsigned short* __restrict__ A2, unsigned char* __restrict__ M8k,
    unsigned char* __restrict__ M8x, int has_mx) {
  const int tn = blockIdx.x, tm = blockIdx.y, b = blockIdx.z;
  const int tid = threadIdx.x, lane = tid & 63;
  const int w = tid >> 6, wr = w >> 1, wc = w & 1;
  const int q = lane >> 4, ln = lane & 15;
  const size_t Ao = (size_t)b * NN * NN;
  __shared__ __align__(16) unsigned char Asw[128 * 128];
  __shared__ __align__(16) unsigned char Bsw[128 * 128];
  f32x4 acc[4][4];
#pragma unroll
  for (int mi = 0; mi < 4; ++mi)
#pragma unroll
    for (int ni = 0; ni < 4; ++ni) acc[mi][ni] = f32x4{0.f, 0.f, 0.f, 0.f};

  const int srow = tid >> 1, sh = tid & 1;
  const unsigned short* A2b = A2 + Ao;
  const unsigned short* Bb = A1T + Ao;

  for (int k0 = 0; k0 < NN; k0 += 64) {
    {
      const unsigned short* asrc = A2b + (size_t)(tm * 128 + srow) * NN + k0 + sh * 32;
      const unsigned short* bsrc = Bb + (size_t)(tn * 128 + srow) * NN + k0 + sh * 32;
      const int sw = srow & 7;
#pragma unroll
      for (int j = 0; j < 4; ++j) {
        u32x4 va = *(const u32x4*)(asrc + j * 8);
        u32x4 vb = *(const u32x4*)(bsrc + j * 8);
        *(u32x4*)(Asw + srow * 128 + (((sh * 4 + j) ^ sw) << 4)) = va;
        *(u32x4*)(Bsw + srow * 128 + (((sh * 4 + j) ^ sw) << 4)) = vb;
      }
    }
    __syncthreads();
#pragma unroll
    for (int ks = 0; ks < 2; ++ks) {
      bf16x8 af[4], bv[4];
#pragma unroll
      for (int mi = 0; mi < 4; ++mi) {
        const int r = wr * 64 + mi * 16 + ln;
        af[mi] = *(const bf16x8*)(Asw + r * 128 + (((ks * 4 + q) ^ (r & 7)) << 4));
      }
#pragma unroll
      for (int ni = 0; ni < 4; ++ni) {
        const int r = wc * 64 + ni * 16 + ln;
        bv[ni] = *(const bf16x8*)(Bsw + r * 128 + (((ks * 4 + q) ^ (r & 7)) << 4));
      }
#pragma unroll
      for (int mi = 0; mi < 4; ++mi)
#pragma unroll
        for (int ni = 0; ni < 4; ++ni)
          acc[mi][ni] = __builtin_amdgcn_mfma_f32_16x16x32_bf16(
              af[mi], bv[ni], acc[mi][ni], 0, 0, 0);
    }
    __syncthreads();
  }
  const float c1 = 1048576.f / (3.f * 512.f * 512.f);
  const float c2 = c1 / 512.f;
  const float c3 = c2 / 512.f;
  unsigned char* Mk = M8k + Ao;
  unsigned char* Mx = M8x + Ao;
#pragma unroll
  for (int mi = 0; mi < 4; ++mi) {
    const int row0 = tm * 128 + wr * 64 + mi * 16 + q * 4;
#pragma unroll
    for (int ni = 0; ni < 4; ++ni) {
      const int col = tn * 128 + wc * 64 + ni * 16 + ln;
      unsigned int wv = 0;
#pragma unroll
      for (int r = 0; r < 4; ++r) {
        const int row = row0 + r;
        float mval = c1 * A1[Ao + (size_t)row * NN + col] +
                     c2 * bf2f(A2b[(size_t)row * NN + col]) + c3 * acc[mi][ni][r];
        wv |= ((unsigned int)e4m3(mval)) << (8 * r);
      }
      *(unsigned int*)(Mk + m8_addr(row0, col)) = wv;
      if (has_mx) *(unsigned int*)(Mx + m8mxa(row0, col)) = wv;
    }
  }
}

// ---------------------------------------------------------------------------
// Slow GEMMs (fallback path; legacy layout, packed stores).
// ---------------------------------------------------------------------------
__global__ __launch_bounds__(256) void gemm_a2_slow(
    const float* __restrict__ A1, unsigned short* __restrict__ A2) {
  const int b = blockIdx.x, tn = blockIdx.y, tm = blockIdx.z;
  const int tid = threadIdx.x, lane = tid & 63, w = tid >> 6;
  const int q = lane >> 4, ln = lane & 15;
  const size_t Ao = (size_t)b * NN * NN;
  f32x4 zero = {0.f, 0.f, 0.f, 0.f};
  f32x4 acc[4] = {zero, zero, zero, zero};
  const float* ap = A1 + Ao + (size_t)(tm * 64 + w * 16 + ln) * NN + q * 8;
  for (int k0 = 0; k0 < NN; k0 += 32) {
    f32x4 x0 = *(const f32x4*)(ap + k0);
    f32x4 x1 = *(const f32x4*)(ap + k0 + 4);
    union { bf16x8 v; unsigned int u[4]; } af;
    af.u[0] = pk_trunc(x0[1], x0[0]);
    af.u[1] = pk_trunc(x0[3], x0[2]);
    af.u[2] = pk_trunc(x1[1], x1[0]);
    af.u[3] = pk_trunc(x1[3], x1[2]);
#pragma unroll
    for (int i = 0; i < 4; ++i) {
      bf16x8 bv;
#pragma unroll
      for (int j = 0; j < 8; ++j)
        bv[j] = (short)f2bf(A1[Ao + (size_t)(k0 + q * 8 + j) * NN + tn * 64 + i * 16 + ln]);
      acc[i] = __builtin_amdgcn_mfma_f32_16x16x32_bf16(af.v, bv, acc[i], 0, 0, 0);
    }
  }
  unsigned short* Cb = A2 + Ao;
#pragma unroll
  for (int i = 0; i < 4; ++i) {
    int col = tn * 64 + i * 16 + ln;
#pragma unroll
    for (int r = 0; r < 4; ++r) {
      int row = tm * 64 + w * 16 + q * 4 + r;
      Cb[(size_t)row * NN + col] = f2bf(acc[i][r]);
    }
  }
}

__global__ __launch_bounds__(256) void gemm_m_slow(
    const float* __restrict__ A1, const unsigned short* __restrict__ A2,
    unsigned char* __restrict__ M8k, unsigned char* __restrict__ M8x,
    int has_mx) {
  const int b = blockIdx.x, tn = blockIdx.y, tm = blockIdx.z;
  const int tid = threadIdx.x, lane = tid & 63, w = tid >> 6;
  const int q = lane >> 4, ln = lane & 15;
  const size_t Ao = (size_t)b * NN * NN;
  const unsigned short* A2b = A2 + Ao;
  f32x4 zero = {0.f, 0.f, 0.f, 0.f};
  f32x4 acc[4] = {zero, zero, zero, zero};
  const unsigned short* ap = A2b + (size_t)(tm * 64 + w * 16 + ln) * NN + q * 8;
  for (int k0 = 0; k0 < NN; k0 += 32) {
    bf16x8 af = *(const bf16x8*)(ap + k0);
#pragma unroll
    for (int i = 0; i < 4; ++i) {
      bf16x8 bv;
#pragma unroll
      for (int j = 0; j < 8; ++j)
        bv[j] = (short)f2bf(A1[Ao + (size_t)(k0 + q * 8 + j) * NN + tn * 64 + i * 16 + ln]);
      acc[i] = __builtin_amdgcn_mfma_f32_16x16x32_bf16(af, bv, acc[i], 0, 0, 0);
    }
  }
  const float c1 = 1048576.f / (3.f * 512.f * 512.f);
  const float c2 = c1 / 512.f;
  const float c3 = c2 / 512.f;
  unsigned char* Mk = M8k + Ao;
  unsigned char* Mx = M8x + Ao;
  const int row0 = tm * 64 + w * 16 + q * 4;
#pragma unroll
  for (int i = 0; i < 4; ++i) {
    int col = tn * 64 + i * 16 + ln;
    unsigned int wv = 0;
#pragma unroll
    for (int r = 0; r < 4; ++r) {
      int row = row0 + r;
      float mval = c1 * A1[Ao + (size_t)row * NN + col] +
                   c2 * bf2f(A2b[(size_t)row * NN + col]) + c3 * acc[i][r];
      wv |= ((unsigned int)e4m3(mval)) << (8 * r);
    }
    *(unsigned int*)(Mk + m8_addr(row0, col)) = wv;
    if (has_mx) *(unsigned int*)(Mx + m8mxa(row0, col)) = wv;
  }
}

// ---------------------------------------------------------------------------
// Probe: HW-verify the assumed K=128 MX layout + scale semantics.
// ---------------------------------------------------------------------------
__global__ __launch_bounds__(64) void probe_kernel(int* __restrict__ flag) {
  const int lane = threadIdx.x, q = lane >> 4, n = lane & 15;
  __shared__ unsigned char A8[128];
  __shared__ unsigned char B8[128 * 16];
  for (int k = lane; k < 128; k += 64) A8[k] = (unsigned char)(8 + ((k * 37 + 11) % 56));
  for (int i = lane; i < 2048; i += 64)
    B8[i] = (unsigned char)(((i & 1) ? 0x80 : 0) | (8 + ((i * 23 + 5) % 56)));
  __syncthreads();
  union { i32x8 v; unsigned char b[32]; } af, bf;
#pragma unroll
  for (int j = 0; j < 32; ++j) {
    af.b[j] = A8[q * 32 + j];
    bf.b[j] = B8[(q * 32 + j) * 16 + n];
  }
  f32x4 acc = {0.f, 0.f, 0.f, 0.f};
  acc = __builtin_amdgcn_mfma_scale_f32_16x16x128_f8f6f4(af.v, bf.v, acc, 0, 0,
                                                         0, 127, 0, 127);
  float ref = 0.f;
  for (int k = 0; k < 128; ++k) ref += dec8(A8[k]) * dec8(B8[k * 16 + n]);
  int ok = 1;
#pragma unroll
  for (int r = 0; r < 4; ++r)
    ok &= (fabsf(acc[r] - ref) <= 1e-3f * fmaxf(fabsf(ref), 1.f)) ? 1 : 0;
  unsigned long long bal = __ballot(ok);
  if (lane == 0) *flag = (bal == ~0ull) ? 1 : 0;
}

// ---------------------------------------------------------------------------
// traj2: ONE WAVE PER BATCH CHAIN, zero barriers in the step loop.
// (round-3/4/9 PROVEN at 169 us — verbatim; do not touch.)
// ---------------------------------------------------------------------------
__global__ __launch_bounds__(64) void traj2_kernel(
    const int* __restrict__ skills, const float* __restrict__ labels,
    const float* __restrict__ emb, const float* __restrict__ ub0g,
    const float* __restrict__ uf0g, const float* __restrict__ w1g,
    const float* __restrict__ b1g, const float* __restrict__ w2g,
    const float* __restrict__ b2g, const float* __restrict__ wfg,
    const float* __restrict__ bfg, const float* __restrict__ wbg,
    const float* __restrict__ bbg, float* __restrict__ UBg,
    float* __restrict__ UFg) {
  const int b = blockIdx.x;
  const int lane = threadIdx.x;
  const int o = lane & 31, half = lane >> 5;

  __shared__ float ub_l[DD], uf_l[DD], e_l[2 * DD];
  __shared__ float label_s[NSTEP];
  __shared__ int skill_s[NSTEP];

  for (int i = lane; i < NSTEP; i += 64) {
    label_s[i] = labels[b * TTOT + i + 1];
    skill_s[i] = skills[b * TTOT + i + 1];
  }

  float w1r[80];
#pragma unroll
  for (int k = 0; k < 8; ++k) {
    const int c0 = (half * 8 + k) * 2;
#pragma unroll
    for (int j = 0; j < 5; ++j) {
      w1r[k * 10 + j] = w1g[o * 160 + c0 * 5 + j];
      w1r[k * 10 + 5 + j] = w1g[o * 160 + (c0 + 1) * 5 + j];
    }
  }
  float w2r[16];
#pragma unroll
  for (int cc = 0; cc < 16; ++cc) w2r[cc] = w2g[o * 32 + half * 16 + cc];
  const float* wsg = half ? wbg : wfg;
  float wsr[32];
#pragma unroll
  for (int c = 0; c < DD; ++c) wsr[c] = wsg[o * 32 + c];
  const float b1r = b1g[o], b2r = b2g[o];
  const float bselr = half ? bbg[o] : bfg[o];

  float val = half ? ub0g[b * DD + o] : uf0g[b * DD + o];

  __syncthreads();

  float* UBp = UBg + (size_t)b * NSTEP * DD;
  float* UFp = UFg + (size_t)b * NSTEP * DD;

  float ev = emb[(size_t)skill_s[0] * (2 * DD) + lane];
  float pg[8];

  for (int step = 0; step < NSTEP; ++step) {
    if (step) {
      float part = 0.f;
#pragma unroll
      for (int s2 = 0; s2 < 8; ++s2) part += pg[s2];
      float h = b1r + part + __shfl_xor(part, 32);
      h = fmaxf(h, 0.f);
      float up = 0.f;
#pragma unroll
      for (int cc = 0; cc < 16; ++cc) {
        float hv0 = rlane(h, cc), hv1 = rlane(h, 16 + cc);
        up += (half ? hv1 : hv0) * w2r[cc];
      }
      float uu = b2r + up + __shfl_xor(up, 32);
      float aac = bselr;
#pragma unroll
      for (int c = 0; c < DD; ++c) aac += rlane(uu, c) * wsr[c];
      val = 1.f - 2.f / (1.f + __expf(2.f * aac));
    }
    if (half) ub_l[o] = val; else uf_l[o] = val;
    e_l[lane] = ev;
    (half ? UBp : UFp)[step * DD + o] = val;
    if (step + 1 < NSTEP) ev = emb[(size_t)skill_s[step + 1] * (2 * DD) + lane];
    const float lab = label_s[step];
#pragma unroll
    for (int k = 0; k < 8; ++k) {
      const int c0 = (half * 8 + k) * 2;
      float ubc0 = ub_l[c0], ubc1 = ub_l[c0 + 1];
      float ufc0 = uf_l[c0], ufc1 = uf_l[c0 + 1];
      float rs0 = e_l[c0], rs1 = e_l[c0 + 1];
      float rr0 = e_l[DD + c0], rr1 = e_l[DD + c0 + 1];
      float hpart = ubc0 * w1r[k * 10 + 0] + ufc0 * w1r[k * 10 + 1] +
                    lab * w1r[k * 10 + 2] + rr0 * w1r[k * 10 + 3] +
                    rs0 * w1r[k * 10 + 4];
      hpart += ubc1 * w1r[k * 10 + 5] + ufc1 * w1r[k * 10 + 6] +
               lab * w1r[k * 10 + 7] + rr1 * w1r[k * 10 + 8] +
               rs1 * w1r[k * 10 + 9];
      pg[k] = hpart;
    }
  }
}

// ---------------------------------------------------------------------------
// P3: scan with precomp FUSED IN.  Each wave loads ub_s into lanes 0-31 and
// uf_{s-1} into lanes 32-63 (one 4B load/thread/step, UB/UF = 3.2 MB = L2-
// resident); ncb/nlf computed per-thread via constant-lane readlanes with
// precomp's EXACT per-accumulator grouping/order -> bit-identical values.
// Eliminates the precomp kernel and the 104 MB NCB/TC HBM round-trip; the
// added VALU issues on the vector pipe under the MFMA chain (m114 overlap).
// ---------------------------------------------------------------------------
__global__ __launch_bounds__(512, 2) void scan_fused(
    const int* __restrict__ skills, const int* __restrict__ times,
    const float* __restrict__ emb, const float* __restrict__ UBg,
    const float* __restrict__ UFg, const unsigned char* __restrict__ M8k,
    const unsigned char* __restrict__ M8x, int allow_mx,
    const int* __restrict__ flag, float* __restrict__ out) {
  const int b = blockIdx.x;
  const int t = threadIdx.x;
  const int lane = t & 63, w = t >> 6, q = lane >> 4;
  __shared__ __align__(32) unsigned char lp8[2][NN];
  __shared__ int skill_s[NSTEP];
  __shared__ float delta_s[NSTEP];
  const int use_mx = allow_mx && (*flag);
  for (int i = t; i < NSTEP; i += 512) {
    skill_s[i] = skills[b * TTOT + i + 1];
    int dt_ = times[b * TTOT + i + 1] - times[b * TTOT + i];
    if (dt_ < 0) dt_ = -dt_;
    delta_s[i] = __logf((float)dt_ + 1e-6f) * 0.6213349345596119f;  // 1/ln 5
  }
  // per-thread node-embedding rows (identical values to precomp's nr/ns)
  float nr[DD], ns[DD];
#pragma unroll
  for (int c = 0; c < DD; ++c) {
    ns[c] = emb[(size_t)t * (2 * DD) + c];
    nr[c] = emb[(size_t)t * (2 * DD) + DD + c];
  }

  union MU { i32x8 v; long l[4]; };
  MU mreg[16];
  if (use_mx) {
    const unsigned char* Mb = M8x + (size_t)b * NN * NN;
#pragma unroll
    for (int c = 0; c < 4; ++c)
#pragma unroll
      for (int i = 0; i < 4; ++i)
        mreg[c * 4 + i].v = *(const i32x8*)(
            Mb + (((size_t)(c * 32 + w * 4 + i) * 64 + lane) << 5));
  } else {
    const unsigned char* Mb = M8k + (size_t)b * NN * NN;
#pragma unroll
    for (int c = 0; c < 16; ++c)
#pragma unroll
      for (int i = 0; i < 4; ++i)
        mreg[c].l[i] = *(const long*)(
            Mb + (((size_t)(w * 64 + i * 16 + c)) << 9) + (size_t)lane * 8);
  }

  const float* UBb = UBg + (size_t)b * NSTEP * DD;
  const float* UFb = UFg + (size_t)b * NSTEP * DD;
  // s=0 rows: lanes 0-31 hold ub_0[c], lanes 32-63 hold uf_0[c]
  float uv = (lane < 32) ? UBb[lane] : UFb[lane - 32];
  float ncb_c, tc_c;
  {
    float n0 = 0.f, n1 = 0.f, n2 = 0.f, n3 = 0.f;
    float l0 = 0.f, l1 = 0.f, l2 = 0.f, l3 = 0.f;
#pragma unroll
    for (int c = 0; c < 8; ++c) {
      n0 += rlane(uv, c) * nr[c];
      n1 += rlane(uv, 8 + c) * nr[8 + c];
      n2 += rlane(uv, 16 + c) * nr[16 + c];
      n3 += rlane(uv, 24 + c) * nr[24 + c];
      l0 += rlane(uv, 32 + c) * ns[c];
      l1 += rlane(uv, 40 + c) * ns[8 + c];
      l2 += rlane(uv, 48 + c) * ns[16 + c];
      l3 += rlane(uv, 56 + c) * ns[24 + c];
    }
    ncb_c = (n0 + n1) + (n2 + n3);
    float nlf = (l0 + l1) + (l2 + l3);
    float rlp0 = ncb_c;  // lp_0 == ncb_0
    lp8[0][t] = e4m3(rlp0);
    __syncthreads();  // lp8 + delta_s ready
    tc_c = __expf(-delta_s[0] * 0.1f * nlf);
  }
  float rlp = ncb_c;

  int pidx = -1;
  float pval = 0.f;
  for (int step = 0; step < NSTEP; ++step) {
    const int cb = step & 1;
    if (pidx >= 0) out[pidx] = pval;
    // prefetch step+1 state rows: ub_{s+1} (lanes 0-31), uf_s (lanes 32-63)
    float uv_n = 0.f;
    if (step + 1 < NSTEP)
      uv_n = (lane < 32) ? UBb[(size_t)(step + 1) * DD + lane]
                         : UFb[(size_t)step * DD + (lane - 32)];
    int sk_s = skill_s[step];
    f32x4 zero = {0.f, 0.f, 0.f, 0.f};
    f32x4 acc[4] = {zero, zero, zero, zero};
    if (use_mx) {
#pragma unroll
      for (int c = 0; c < 4; ++c) {
        i32x8 af = *(const i32x8*)(&lp8[cb][c * 128 + q * 32]);
#pragma unroll
        for (int i = 0; i < 4; ++i)
          acc[i] = __builtin_amdgcn_mfma_scale_f32_16x16x128_f8f6f4(
              af, mreg[c * 4 + i].v, acc[i], 0, 0, 0, 127, 0, 127);
      }
    } else {
#pragma unroll
      for (int c = 0; c < 16; ++c) {
        long af = *(const long*)(&lp8[cb][c * 32 + q * 8]);
#pragma unroll
        for (int i = 0; i < 4; ++i)
          acc[i] = __builtin_amdgcn_mfma_f32_16x16x32_fp8_fp8(af, mreg[c].l[i],
                                                              acc[i], 0, 0, 0);
      }
    }
    float spatial = ((q & 2) ? ((q & 1) ? acc[3][0] : acc[2][0])
                             : ((q & 1) ? acc[1][0] : acc[0][0])) * 0x1p-20f;
    float cur = 1.f / (1.f + __expf(-((ncb_c + tc_c * rlp) + spatial)));
    pidx = (t == sk_s) ? (step * BSZ + b) : -1;
    pval = cur;
    rlp = cur;
    lp8[cb ^ 1][t] = e4m3(cur);
    __syncthreads();
    // compute next step's ncb/tc from the prefetched rows (precomp's order)
    if (step + 1 < NSTEP) {
      float m0 = 0.f, m1 = 0.f, m2 = 0.f, m3 = 0.f;
      float k0 = 0.f, k1 = 0.f, k2 = 0.f, k3 = 0.f;
#pragma unroll
      for (int c = 0; c < 8; ++c) {
        m0 += rlane(uv_n, c) * nr[c];
        m1 += rlane(uv_n, 8 + c) * nr[8 + c];
        m2 += rlane(uv_n, 16 + c) * nr[16 + c];
        m3 += rlane(uv_n, 24 + c) * nr[24 + c];
        k0 += rlane(uv_n, 32 + c) * ns[c];
        k1 += rlane(uv_n, 40 + c) * ns[8 + c];
        k2 += rlane(uv_n, 48 + c) * ns[16 + c];
        k3 += rlane(uv_n, 56 + c) * ns[24 + c];
      }
      ncb_c = (m0 + m1) + (m2 + m3);
      float nlf = (k0 + k1) + (k2 + k3);
      tc_c = __expf(-delta_s[step + 1] * 0.1f * nlf);
    }
  }
  if (pidx >= 0) out[pidx] = pval;
}

// ---------------------------------------------------------------------------
// LEGACY scan — retained verbatim for low-workspace tiers.
// ---------------------------------------------------------------------------
__global__ __launch_bounds__(512, 2) void scan_kernel(
    const int* __restrict__ skills, const int* __restrict__ times,
    const float* __restrict__ labels, const float* __restrict__ emb,
    const float* __restrict__ ub0g, const float* __restrict__ uf0g,
    const float* __restrict__ w1g, const float* __restrict__ b1g,
    const float* __restrict__ w2g, const float* __restrict__ b2g,
    const float* __restrict__ wfg, const float* __restrict__ bfg,
    const float* __restrict__ wbg, const float* __restrict__ bbg,
    const unsigned char* __restrict__ M8k, const unsigned char* __restrict__ M8x,
    int allow_mx, const int* __restrict__ flag, float* __restrict__ out) {
  const int b = blockIdx.x;
  const int t = threadIdx.x;
  const int lane = t & 63, w = t >> 6, q = lane >> 4;

  __shared__ __align__(32) unsigned char lp8[NN];
  __shared__ float ub[DD], uf[DD];
  __shared__ float delta_s[NSTEP], label_s[NSTEP];
  __shared__ int skill_s[NSTEP];
  __shared__ float hp[16][33];
  __shared__ float w1t[DD * 5 * DD];
  __shared__ float w2t[DD * DD], wft[DD * DD], wbt[DD * DD];
  __shared__ float b1s[DD], b2s[DD], bfs[DD], bbs[DD];

  const int use_mx = allow_mx && (*flag);

  float nrec[DD], nsend[DD];
#pragma unroll
  for (int c = 0; c < DD; ++c) {
    nsend[c] = emb[(size_t)t * (2 * DD) + c];
    nrec[c] = emb[(size_t)t * (2 * DD) + DD + c];
  }
  for (int idx = t; idx < DD * DD * 5; idx += 512) {
    int o = idx / 160, rem = idx % 160;
    w1t[rem * 32 + o] = w1g[idx];
  }
  for (int idx = t; idx < DD * DD; idx += 512) {
    int o = idx >> 5, c = idx & 31;
    w2t[c * 32 + o] = w2g[idx];
    wft[c * 32 + o] = wfg[idx];
    wbt[c * 32 + o] = wbg[idx];
  }
  if (t < DD) {
    b1s[t] = b1g[t]; b2s[t] = b2g[t];
    bfs[t] = bfg[t]; bbs[t] = bbg[t];
    ub[t] = ub0g[b * DD + t];
    uf[t] = uf0g[b * DD + t];
  }
  for (int i = t; i < NSTEP; i += 512) {
    int dt_ = times[b * TTOT + i + 1] - times[b * TTOT + i];
    if (dt_ < 0) dt_ = -dt_;
    delta_s[i] = __logf((float)dt_ + 1e-6f) * 0.6213349345596119f;
    label_s[i] = labels[b * TTOT + i + 1];
    skill_s[i] = skills[b * TTOT + i + 1];
  }

  union MU { i32x8 v; long l[4]; };
  MU mreg[16];
  if (use_mx) {
    const unsigned char* Mb = M8x + (size_t)b * NN * NN;
#pragma unroll
    for (int c = 0; c < 4; ++c)
#pragma unroll
      for (int i = 0; i < 4; ++i)
        mreg[c * 4 + i].v = *(const i32x8*)(
            Mb + (((size_t)(c * 32 + w * 4 + i) * 64 + lane) << 5));
  } else {
    const unsigned char* Mb = M8k + (size_t)b * NN * NN;
#pragma unroll
    for (int c = 0; c < 16; ++c)
#pragma unroll
      for (int i = 0; i < 4; ++i)
        mreg[c].l[i] = *(const long*)(
            Mb + (((size_t)(w * 64 + i * 16 + c)) << 9) + (size_t)lane * 8);
  }
  __syncthreads();

  float rlp = 0.f, rnlf = 0.f;
#pragma unroll
  for (int c = 0; c < DD; ++c) {
    rlp += ub[c] * nrec[c];
    rnlf += uf[c] * nsend[c];
  }
  lp8[t] = e4m3(rlp);
  __syncthreads();

  for (int step = 0; step < NSTEP; ++step) {
    if (step && w == 0) {
      int o = lane & 31, half = lane >> 5;
      float part = 0.f;
#pragma unroll
      for (int s2 = 0; s2 < 8; ++s2) part += hp[half * 8 + s2][o];
      float h = b1s[o] + part + __shfl_xor(part, 32);
      h = fmaxf(h, 0.f);
      float up = 0.f;
#pragma unroll
      for (int cc = 0; cc < 16; ++cc) {
        float hv0 = rlane(h, cc), hv1 = rlane(h, 16 + cc);
        up += (half ? hv1 : hv0) * w2t[(half * 16 + cc) * 32 + o];
      }
      float uu = b2s[o] + up + __shfl_xor(up, 32);
      const float* wsel = half ? wbt : wft;
      float aac = half ? bbs[o] : bfs[o];
#pragma unroll
      for (int c = 0; c < DD; ++c) aac += rlane(uu, c) * wsel[c * 32 + o];
      float val = 1.f - 2.f / (1.f + __expf(2.f * aac));
      if (half) ub[o] = val;
      else uf[o] = val;
    }
    f32x4 zero = {0.f, 0.f, 0.f, 0.f};
    f32x4 acc[4] = {zero, zero, zero, zero};
    if (use_mx) {
#pragma unroll
      for (int c = 0; c < 4; ++c) {
        i32x8 af = *(const i32x8*)(&lp8[c * 128 + q * 32]);
#pragma unroll
        for (int i = 0; i < 4; ++i)
          acc[i] = __builtin_amdgcn_mfma_scale_f32_16x16x128_f8f6f4(
              af, mreg[c * 4 + i].v, acc[i], 0, 0, 0, 127, 0, 127);
      }
    } else {
#pragma unroll
      for (int c = 0; c < 16; ++c) {
        long af = *(const long*)(&lp8[c * 32 + q * 8]);
#pragma unroll
        for (int i = 0; i < 4; ++i)
          acc[i] = __builtin_amdgcn_mfma_f32_16x16x32_fp8_fp8(af, mreg[c].l[i],
                                                              acc[i], 0, 0, 0);
      }
    }
    float spatial = ((q & 2) ? ((q & 1) ? acc[3][0] : acc[2][0])
                             : ((q & 1) ? acc[1][0] : acc[0][0])) * 0x1p-20f;
    __syncthreads();

    float rub = ub[lane & 31], ruf = uf[lane & 31];
    float n0 = 0.f, n1 = 0.f, n2 = 0.f, n3 = 0.f;
    float l0 = 0.f, l1 = 0.f, l2 = 0.f, l3 = 0.f;
#pragma unroll
    for (int c = 0; c < 8; ++c) {
      n0 += rlane(rub, c) * nrec[c];
      n1 += rlane(rub, 8 + c) * nrec[8 + c];
      n2 += rlane(rub, 16 + c) * nrec[16 + c];
      n3 += rlane(rub, 24 + c) * nrec[24 + c];
      l0 += rlane(ruf, c) * nsend[c];
      l1 += rlane(ruf, 8 + c) * nsend[8 + c];
      l2 += rlane(ruf, 16 + c) * nsend[16 + c];
      l3 += rlane(ruf, 24 + c) * nsend[24 + c];
    }
    float ncb = (n0 + n1) + (n2 + n3);
    float nlfn = (l0 + l1) + (l2 + l3);
    float e = __expf(-delta_s[step] * 0.1f * rnlf) * rlp;
    float cur = 1.f / (1.f + __expf(-(ncb + e + spatial)));

    {
      int o = t & 31, s = t >> 5;
      float lab = label_s[step];
      int sk = skill_s[step];
      float hpart = 0.f;
#pragma unroll
      for (int cc = 0; cc < 2; ++cc) {
        int c = (s << 1) + cc;
        const float* wrow = &w1t[(c * 5) * 32 + o];
        float rs = emb[(size_t)sk * (2 * DD) + c];
        float rr = emb[(size_t)sk * (2 * DD) + DD + c];
        hpart += ub[c] * wrow[0] + uf[c] * wrow[32] + lab * wrow[64] +
                 rr * wrow[96] + rs * wrow[128];
      }
      hp[s][o] = hpart;
    }

    rlp = cur;
    rnlf = nlfn;
    lp8[t] = e4m3(cur);
    if (t == skill_s[step]) out[step * BSZ + b] = cur;
    __syncthreads();
  }
}

extern "C" void kernel_launch(void* const* d_in, const int* in_sizes, int n_in,
                              void* d_out, int out_size, void* d_ws, size_t ws_size,
                              hipStream_t stream) {
  (void)in_sizes; (void)n_in; (void)out_size;
  const int* skills = (const int*)d_in[0];
  const int* times = (const int*)d_in[1];
  const float* labels = (const float*)d_in[2];
  const float* adj = (const float*)d_in[3];
  const float* emb = (const float*)d_in[4];
  const float* ub0 = (const float*)d_in[5];
  const float* uf0 = (const float*)d_in[6];
  const float* w1 = (const float*)d_in[7];
  const float* b1 = (const float*)d_in[8];
  const float* w2 = (const float*)d_in[9];
  const float* b2 = (const float*)d_in[10];
  const float* wf = (const float*)d_in[11];
  const float* bf = (const float*)d_in[12];
  const float* wb = (const float*)d_in[13];
  const float* bb = (const float*)d_in[14];

  const size_t mat = (size_t)BSZ * NN * NN;                        // 16,777,216
  const size_t ncb_sz = (size_t)BSZ * NSTEP * NN * sizeof(float);  // 26,083,328
  const size_t ub_sz = (size_t)BSZ * NSTEP * DD * sizeof(float);   //  1,630,208
  char* base = (char*)d_ws;
  unsigned char *M8k, *M8x;
  unsigned short *A2, *A1T = nullptr;
  char* ovl = nullptr;  // A2+A1T region, dead after gemm_m -> UB/UF overlay
  int* flag;
  int use_fast, allow_mx;
  if (ws_size >= 6 * mat + 4) {          // fast gemms + MX
    use_fast = 1; allow_mx = 1;
    M8k = (unsigned char*)base; M8x = M8k + mat;
    A2 = (unsigned short*)(base + 2 * mat);
    A1T = (unsigned short*)(base + 4 * mat);
    flag = (int*)(base + 6 * mat);
    ovl = base + 2 * mat;
  } else if (ws_size >= 5 * mat + 4) {   // fast gemms, no MX
    use_fast = 1; allow_mx = 0;
    M8k = (unsigned char*)base; M8x = M8k;
    A2 = (unsigned short*)(base + mat);
    A1T = (unsigned short*)(base + 3 * mat);
    flag = (int*)(base + 5 * mat);
    ovl = base + mat;
  } else if (ws_size >= 4 * mat + 4) {   // slow gemms + MX (legacy scan)
    use_fast = 0; allow_mx = 1;
    M8k = (unsigned char*)base; M8x = M8k + mat;
    A2 = (unsigned short*)(base + 2 * mat);
    flag = (int*)(base + 4 * mat);
  } else {                               // slow, no MX (legacy scan)
    use_fast = 0; allow_mx = 0;
    M8k = (unsigned char*)base; M8x = M8k;
    A2 = (unsigned short*)(base + mat);
    flag = (int*)(base + 3 * mat);
  }

  dim3 gb(256);
  if (use_fast) {
    dim3 gt(8, 8, BSZ);   // transpose: 64-tiles
    dim3 gf(4, 4, BSZ);   // staged gemms: 128-tiles, batch-adjacent
    transpose_kernel<<<gt, gb, 0, stream>>>(adj, A1T);
    gemm_a2_fast<<<gf, gb, 0, stream>>>(adj, A1T, A2);
    gemm_m_fast<<<gf, gb, 0, stream>>>(adj, A1T, A2, M8k, M8x, allow_mx);
    float* UB = (float*)(ovl + 2 * ncb_sz);
    float* UF = (float*)(ovl + 2 * ncb_sz + ub_sz);
    traj2_kernel<<<dim3(BSZ), dim3(64), 0, stream>>>(
        skills, labels, emb, ub0, uf0, w1, b1, w2, b2, wf, bf, wb, bb, UB, UF);
    probe_kernel<<<dim3(1), dim3(64), 0, stream>>>(flag);
    scan_fused<<<dim3(BSZ), dim3(512), 0, stream>>>(
        skills, times, emb, UB, UF, M8k, M8x, allow_mx, flag, (float*)d_out);
  } else {
    dim3 gg(BSZ, 8, 8);
    gemm_a2_slow<<<gg, gb, 0, stream>>>(adj, A2);
    gemm_m_slow<<<gg, gb, 0, stream>>>(adj, A2, M8k, M8x, allow_mx);
    probe_kernel<<<dim3(1), dim3(64), 0, stream>>>(flag);
    scan_kernel<<<dim3(BSZ), dim3(512), 0, stream>>>(
        skills, times, labels, emb, ub0, uf0, w1, b1, w2, b2, wf, bf, wb, bb,
        M8k, M8x, allow_mx, flag, (float*)d_out);
  }
}

// Round 11
// 649.691 us; speedup vs baseline: 1.0450x; 1.0450x over previous
//
#include <hip/hip_runtime.h>

#define NN 512
#define BSZ 64
#define TTOT 200
#define NSTEP 199
#define DD 32

typedef __attribute__((ext_vector_type(8))) short bf16x8;
typedef __attribute__((ext_vector_type(8))) int i32x8;
typedef __attribute__((ext_vector_type(4))) float f32x4;
typedef __attribute__((ext_vector_type(4))) unsigned int u32x4;

__device__ __forceinline__ float bf2f(unsigned short u) {
  union { unsigned int i; float f; } v; v.i = ((unsigned int)u) << 16; return v.f;
}
__device__ __forceinline__ unsigned short f2bf(float f) {  // RNE
  unsigned int b = __float_as_uint(f);
  return (unsigned short)((b + 0x7fffu + ((b >> 16) & 1u)) >> 16);
}
__device__ __forceinline__ unsigned int pk_trunc(float hi, float lo) {
  return __builtin_amdgcn_perm(__float_as_uint(hi), __float_as_uint(lo), 0x07060302u);
}
// f32 -> OCP e4m3 (RNE on normals; flush tiny to 0; clamp 448)
__device__ __forceinline__ unsigned char e4m3(float x) {
  float a = fabsf(x);
  unsigned int s = (__float_as_uint(x) >> 24) & 0x80u;
  if (a < 0.01171875f) return (unsigned char)s;
  a = fminf(a, 448.0f);
  unsigned int u = __float_as_uint(a);
  unsigned int keep = (u >> 20) & 7u;
  unsigned int rest = u & 0xFFFFFu;
  unsigned int base = (((u >> 23) - 120u) << 3) | keep;
  unsigned int rnd = (rest > 0x80000u) || (rest == 0x80000u && (keep & 1u));
  return (unsigned char)(s | (base + rnd));
}
__device__ __forceinline__ float dec8(unsigned char x) {  // e4m3 -> f32
  int e = (x >> 3) & 15, m = x & 7;
  float v = e ? ldexpf(8.f + (float)m, e - 10) : ldexpf((float)m, -9);
  return (x & 0x80) ? -v : v;
}
__device__ __forceinline__ float rlane(float v, int l) {
  return __int_as_float(__builtin_amdgcn_readlane(__float_as_int(v), l));
}

// K=32 fp8 B-frag layout (round-4 HW-PROVEN)
__device__ __forceinline__ size_t m8_addr(int k, int col) {
  int nt = col >> 4, cch = k >> 5;
  int l2 = (((k >> 3) & 3) << 4) + (col & 15);
  return (size_t)((nt * 16 + cch) * 512) + (size_t)l2 * 8 + (size_t)(k & 7);
}
// K=128 MX B-frag layout (probe-verified)
__device__ __forceinline__ size_t m8mxa(int k, int col) {
  int f = ((k >> 7) << 5) + (col >> 4);
  int ln2 = (((k >> 5) & 3) << 4) + (col & 15);
  return (((size_t)f * 64 + ln2) << 5) + (size_t)(k & 31);
}

// ---------------------------------------------------------------------------
// Transpose+convert: A1 (f32 [b][r][c]) -> A1T (bf16 [b][c][r]).
// ---------------------------------------------------------------------------
__global__ __launch_bounds__(256) void transpose_kernel(
    const float* __restrict__ A1, unsigned short* __restrict__ A1T) {
  const int b = blockIdx.z, ct = blockIdx.x * 64, rt = blockIdx.y * 64;
  const int t = threadIdx.x;
  __shared__ unsigned int tl[64][33];
  {
    const int rp = t >> 3, cs = (t & 7) * 8;
    const float* p0 = A1 + (size_t)b * NN * NN + (size_t)(rt + 2 * rp) * NN + ct + cs;
    f32x4 a0 = *(const f32x4*)p0, a1 = *(const f32x4*)(p0 + 4);
    f32x4 b0 = *(const f32x4*)(p0 + NN), b1 = *(const f32x4*)(p0 + NN + 4);
#pragma unroll
    for (int j = 0; j < 4; ++j) {
      tl[cs + j][rp] = pk_trunc(b0[j], a0[j]);
      tl[cs + 4 + j][rp] = pk_trunc(b1[j], a1[j]);
    }
  }
  __syncthreads();
  {
    const int c = t >> 2, rps = (t & 3) * 8;
    unsigned int v[8];
#pragma unroll
    for (int j = 0; j < 8; ++j) v[j] = tl[c][rps + j];
    unsigned int* dst = (unsigned int*)(A1T + (size_t)b * NN * NN +
                                        (size_t)(ct + c) * NN + rt) + rps;
    *(u32x4*)dst = u32x4{v[0], v[1], v[2], v[3]};
    *(u32x4*)(dst + 4) = u32x4{v[4], v[5], v[6], v[7]};
  }
}

// ---------------------------------------------------------------------------
// GEMM 1 fast (LDS-staged): A2 = A1@A1, bf16 out.  128x128 tile, BK=64,
// 4 waves (2x2).  Bit-identical MFMA sequence to the proven direct version.
// ---------------------------------------------------------------------------
__global__ __launch_bounds__(256) void gemm_a2_fast(
    const float* __restrict__ A1, const unsigned short* __restrict__ A1T,
    unsigned short* __restrict__ A2) {
  const int tn = blockIdx.x, tm = blockIdx.y, b = blockIdx.z;
  const int tid = threadIdx.x, lane = tid & 63;
  const int w = tid >> 6, wr = w >> 1, wc = w & 1;
  const int q = lane >> 4, ln = lane & 15;
  const size_t Ao = (size_t)b * NN * NN;
  __shared__ __align__(16) unsigned char Asw[128 * 128];
  __shared__ __align__(16) unsigned char Bsw[128 * 128];
  f32x4 acc[4][4];
#pragma unroll
  for (int mi = 0; mi < 4; ++mi)
#pragma unroll
    for (int ni = 0; ni < 4; ++ni) acc[mi][ni] = f32x4{0.f, 0.f, 0.f, 0.f};

  const int arow = tid >> 2, achk = tid & 3;
  const int brow = tid >> 1, bh = tid & 1;
  const float* Ab = A1 + Ao;
  const unsigned short* Bb = A1T + Ao;

  for (int k0 = 0; k0 < NN; k0 += 64) {
#pragma unroll
    for (int p = 0; p < 2; ++p) {
      const int r = arow + p * 64;
      const float* src = Ab + (size_t)(tm * 128 + r) * NN + k0 + achk * 16;
      f32x4 x0 = *(const f32x4*)src, x1 = *(const f32x4*)(src + 4);
      f32x4 x2 = *(const f32x4*)(src + 8), x3 = *(const f32x4*)(src + 12);
      u32x4 y0 = u32x4{pk_trunc(x0[1], x0[0]), pk_trunc(x0[3], x0[2]),
                       pk_trunc(x1[1], x1[0]), pk_trunc(x1[3], x1[2])};
      u32x4 y1 = u32x4{pk_trunc(x2[1], x2[0]), pk_trunc(x2[3], x2[2]),
                       pk_trunc(x3[1], x3[0]), pk_trunc(x3[3], x3[2])};
      const int sw = r & 7;
      *(u32x4*)(Asw + r * 128 + (((achk * 2) ^ sw) << 4)) = y0;
      *(u32x4*)(Asw + r * 128 + (((achk * 2 + 1) ^ sw) << 4)) = y1;
    }
    {
      const unsigned short* src = Bb + (size_t)(tn * 128 + brow) * NN + k0 + bh * 32;
      const int sw = brow & 7;
#pragma unroll
      for (int j = 0; j < 4; ++j) {
        u32x4 v = *(const u32x4*)(src + j * 8);
        *(u32x4*)(Bsw + brow * 128 + (((bh * 4 + j) ^ sw) << 4)) = v;
      }
    }
    __syncthreads();
#pragma unroll
    for (int ks = 0; ks < 2; ++ks) {
      bf16x8 af[4], bv[4];
#pragma unroll
      for (int mi = 0; mi < 4; ++mi) {
        const int r = wr * 64 + mi * 16 + ln;
        af[mi] = *(const bf16x8*)(Asw + r * 128 + (((ks * 4 + q) ^ (r & 7)) << 4));
      }
#pragma unroll
      for (int ni = 0; ni < 4; ++ni) {
        const int r = wc * 64 + ni * 16 + ln;
        bv[ni] = *(const bf16x8*)(Bsw + r * 128 + (((ks * 4 + q) ^ (r & 7)) << 4));
      }
#pragma unroll
      for (int mi = 0; mi < 4; ++mi)
#pragma unroll
        for (int ni = 0; ni < 4; ++ni)
          acc[mi][ni] = __builtin_amdgcn_mfma_f32_16x16x32_bf16(
              af[mi], bv[ni], acc[mi][ni], 0, 0, 0);
    }
    __syncthreads();
  }
  unsigned short* Cb = A2 + Ao;
#pragma unroll
  for (int mi = 0; mi < 4; ++mi)
#pragma unroll
    for (int ni = 0; ni < 4; ++ni) {
      const int col = tn * 128 + wc * 64 + ni * 16 + ln;
#pragma unroll
      for (int r = 0; r < 4; ++r) {
        const int row = tm * 128 + wr * 64 + mi * 16 + q * 4 + r;
        Cb[(size_t)row * NN + col] = f2bf(acc[mi][ni][r]);
      }
    }
}

// ---------------------------------------------------------------------------
// GEMM 2 fast (LDS-staged): A3 = A2@A1; M*2^20 -> e4m3 dual layouts.
// ---------------------------------------------------------------------------
__global__ __launch_bounds__(256) void gemm_m_fast(
    const float* __restrict__ A1, const unsigned short* __restrict__ A1T,
    const unsigned short* __restrict__ A2, unsigned char* __restrict__ M8k,
    unsigned char* __restrict__ M8x, int has_mx) {
  const int tn = blockIdx.x, tm = blockIdx.y, b = blockIdx.z;
  const int tid = threadIdx.x, lane = tid & 63;
  const int w = tid >> 6, wr = w >> 1, wc = w & 1;
  const int q = lane >> 4, ln = lane & 15;
  const size_t Ao = (size_t)b * NN * NN;
  __shared__ __align__(16) unsigned char Asw[128 * 128];
  __shared__ __align__(16) unsigned char Bsw[128 * 128];
  f32x4 acc[4][4];
#pragma unroll
  for (int mi = 0; mi < 4; ++mi)
#pragma unroll
    for (int ni = 0; ni < 4; ++ni) acc[mi][ni] = f32x4{0.f, 0.f, 0.f, 0.f};

  const int srow = tid >> 1, sh = tid & 1;
  const unsigned short* A2b = A2 + Ao;
  const unsigned short* Bb = A1T + Ao;

  for (int k0 = 0; k0 < NN; k0 += 64) {
    {
      const unsigned short* asrc = A2b + (size_t)(tm * 128 + srow) * NN + k0 + sh * 32;
      const unsigned short* bsrc = Bb + (size_t)(tn * 128 + srow) * NN + k0 + sh * 32;
      const int sw = srow & 7;
#pragma unroll
      for (int j = 0; j < 4; ++j) {
        u32x4 va = *(const u32x4*)(asrc + j * 8);
        u32x4 vb = *(const u32x4*)(bsrc + j * 8);
        *(u32x4*)(Asw + srow * 128 + (((sh * 4 + j) ^ sw) << 4)) = va;
        *(u32x4*)(Bsw + srow * 128 + (((sh * 4 + j) ^ sw) << 4)) = vb;
      }
    }
    __syncthreads();
#pragma unroll
    for (int ks = 0; ks < 2; ++ks) {
      bf16x8 af[4], bv[4];
#pragma unroll
      for (int mi = 0; mi < 4; ++mi) {
        const int r = wr * 64 + mi * 16 + ln;
        af[mi] = *(const bf16x8*)(Asw + r * 128 + (((ks * 4 + q) ^ (r & 7)) << 4));
      }
#pragma unroll
      for (int ni = 0; ni < 4; ++ni) {
        const int r = wc * 64 + ni * 16 + ln;
        bv[ni] = *(const bf16x8*)(Bsw + r * 128 + (((ks * 4 + q) ^ (r & 7)) << 4));
      }
#pragma unroll
      for (int mi = 0; mi < 4; ++mi)
#pragma unroll
        for (int ni = 0; ni < 4; ++ni)
          acc[mi][ni] = __builtin_amdgcn_mfma_f32_16x16x32_bf16(
              af[mi], bv[ni], acc[mi][ni], 0, 0, 0);
    }
    __syncthreads();
  }
  const float c1 = 1048576.f / (3.f * 512.f * 512.f);
  const float c2 = c1 / 512.f;
  const float c3 = c2 / 512.f;
  unsigned char* Mk = M8k + Ao;
  unsigned char* Mx = M8x + Ao;
#pragma unroll
  for (int mi = 0; mi < 4; ++mi) {
    const int row0 = tm * 128 + wr * 64 + mi * 16 + q * 4;
#pragma unroll
    for (int ni = 0; ni < 4; ++ni) {
      const int col = tn * 128 + wc * 64 + ni * 16 + ln;
      unsigned int wv = 0;
#pragma unroll
      for (int r = 0; r < 4; ++r) {
        const int row = row0 + r;
        float mval = c1 * A1[Ao + (size_t)row * NN + col] +
                     c2 * bf2f(A2b[(size_t)row * NN + col]) + c3 * acc[mi][ni][r];
        wv |= ((unsigned int)e4m3(mval)) << (8 * r);
      }
      *(unsigned int*)(Mk + m8_addr(row0, col)) = wv;
      if (has_mx) *(unsigned int*)(Mx + m8mxa(row0, col)) = wv;
    }
  }
}

// ---------------------------------------------------------------------------
// Slow GEMMs (fallback path; legacy layout, packed stores).
// ---------------------------------------------------------------------------
__global__ __launch_bounds__(256) void gemm_a2_slow(
    const float* __restrict__ A1, unsigned short* __restrict__ A2) {
  const int b = blockIdx.x, tn = blockIdx.y, tm = blockIdx.z;
  const int tid = threadIdx.x, lane = tid & 63, w = tid >> 6;
  const int q = lane >> 4, ln = lane & 15;
  const size_t Ao = (size_t)b * NN * NN;
  f32x4 zero = {0.f, 0.f, 0.f, 0.f};
  f32x4 acc[4] = {zero, zero, zero, zero};
  const float* ap = A1 + Ao + (size_t)(tm * 64 + w * 16 + ln) * NN + q * 8;
  for (int k0 = 0; k0 < NN; k0 += 32) {
    f32x4 x0 = *(const f32x4*)(ap + k0);
    f32x4 x1 = *(const f32x4*)(ap + k0 + 4);
    union { bf16x8 v; unsigned int u[4]; } af;
    af.u[0] = pk_trunc(x0[1], x0[0]);
    af.u[1] = pk_trunc(x0[3], x0[2]);
    af.u[2] = pk_trunc(x1[1], x1[0]);
    af.u[3] = pk_trunc(x1[3], x1[2]);
#pragma unroll
    for (int i = 0; i < 4; ++i) {
      bf16x8 bv;
#pragma unroll
      for (int j = 0; j < 8; ++j)
        bv[j] = (short)f2bf(A1[Ao + (size_t)(k0 + q * 8 + j) * NN + tn * 64 + i * 16 + ln]);
      acc[i] = __builtin_amdgcn_mfma_f32_16x16x32_bf16(af.v, bv, acc[i], 0, 0, 0);
    }
  }
  unsigned short* Cb = A2 + Ao;
#pragma unroll
  for (int i = 0; i < 4; ++i) {
    int col = tn * 64 + i * 16 + ln;
#pragma unroll
    for (int r = 0; r < 4; ++r) {
      int row = tm * 64 + w * 16 + q * 4 + r;
      Cb[(size_t)row * NN + col] = f2bf(acc[i][r]);
    }
  }
}

__global__ __launch_bounds__(256) void gemm_m_slow(
    const float* __restrict__ A1, const unsigned short* __restrict__ A2,
    unsigned char* __restrict__ M8k, unsigned char* __restrict__ M8x,
    int has_mx) {
  const int b = blockIdx.x, tn = blockIdx.y, tm = blockIdx.z;
  const int tid = threadIdx.x, lane = tid & 63, w = tid >> 6;
  const int q = lane >> 4, ln = lane & 15;
  const size_t Ao = (size_t)b * NN * NN;
  const unsigned short* A2b = A2 + Ao;
  f32x4 zero = {0.f, 0.f, 0.f, 0.f};
  f32x4 acc[4] = {zero, zero, zero, zero};
  const unsigned short* ap = A2b + (size_t)(tm * 64 + w * 16 + ln) * NN + q * 8;
  for (int k0 = 0; k0 < NN; k0 += 32) {
    bf16x8 af = *(const bf16x8*)(ap + k0);
#pragma unroll
    for (int i = 0; i < 4; ++i) {
      bf16x8 bv;
#pragma unroll
      for (int j = 0; j < 8; ++j)
        bv[j] = (short)f2bf(A1[Ao + (size_t)(k0 + q * 8 + j) * NN + tn * 64 + i * 16 + ln]);
      acc[i] = __builtin_amdgcn_mfma_f32_16x16x32_bf16(af, bv, acc[i], 0, 0, 0);
    }
  }
  const float c1 = 1048576.f / (3.f * 512.f * 512.f);
  const float c2 = c1 / 512.f;
  const float c3 = c2 / 512.f;
  unsigned char* Mk = M8k + Ao;
  unsigned char* Mx = M8x + Ao;
  const int row0 = tm * 64 + w * 16 + q * 4;
#pragma unroll
  for (int i = 0; i < 4; ++i) {
    int col = tn * 64 + i * 16 + ln;
    unsigned int wv = 0;
#pragma unroll
    for (int r = 0; r < 4; ++r) {
      int row = row0 + r;
      float mval = c1 * A1[Ao + (size_t)row * NN + col] +
                   c2 * bf2f(A2b[(size_t)row * NN + col]) + c3 * acc[i][r];
      wv |= ((unsigned int)e4m3(mval)) << (8 * r);
    }
    *(unsigned int*)(Mk + m8_addr(row0, col)) = wv;
    if (has_mx) *(unsigned int*)(Mx + m8mxa(row0, col)) = wv;
  }
}

// ---------------------------------------------------------------------------
// Probe: HW-verify the assumed K=128 MX layout + scale semantics.
// ---------------------------------------------------------------------------
__global__ __launch_bounds__(64) void probe_kernel(int* __restrict__ flag) {
  const int lane = threadIdx.x, q = lane >> 4, n = lane & 15;
  __shared__ unsigned char A8[128];
  __shared__ unsigned char B8[128 * 16];
  for (int k = lane; k < 128; k += 64) A8[k] = (unsigned char)(8 + ((k * 37 + 11) % 56));
  for (int i = lane; i < 2048; i += 64)
    B8[i] = (unsigned char)(((i & 1) ? 0x80 : 0) | (8 + ((i * 23 + 5) % 56)));
  __syncthreads();
  union { i32x8 v; unsigned char b[32]; } af, bf;
#pragma unroll
  for (int j = 0; j < 32; ++j) {
    af.b[j] = A8[q * 32 + j];
    bf.b[j] = B8[(q * 32 + j) * 16 + n];
  }
  f32x4 acc = {0.f, 0.f, 0.f, 0.f};
  acc = __builtin_amdgcn_mfma_scale_f32_16x16x128_f8f6f4(af.v, bf.v, acc, 0, 0,
                                                         0, 127, 0, 127);
  float ref = 0.f;
  for (int k = 0; k < 128; ++k) ref += dec8(A8[k]) * dec8(B8[k * 16 + n]);
  int ok = 1;
#pragma unroll
  for (int r = 0; r < 4; ++r)
    ok &= (fabsf(acc[r] - ref) <= 1e-3f * fmaxf(fabsf(ref), 1.f)) ? 1 : 0;
  unsigned long long bal = __ballot(ok);
  if (lane == 0) *flag = (bal == ~0ull) ? 1 : 0;
}

// ---------------------------------------------------------------------------
// traj2: ONE WAVE PER BATCH CHAIN, zero barriers in the step loop.
// (round-3/4/9 PROVEN at 169 us — verbatim; do not touch.)
// ---------------------------------------------------------------------------
__global__ __launch_bounds__(64) void traj2_kernel(
    const int* __restrict__ skills, const float* __restrict__ labels,
    const float* __restrict__ emb, const float* __restrict__ ub0g,
    const float* __restrict__ uf0g, const float* __restrict__ w1g,
    const float* __restrict__ b1g, const float* __restrict__ w2g,
    const float* __restrict__ b2g, const float* __restrict__ wfg,
    const float* __restrict__ bfg, const float* __restrict__ wbg,
    const float* __restrict__ bbg, float* __restrict__ UBg,
    float* __restrict__ UFg) {
  const int b = blockIdx.x;
  const int lane = threadIdx.x;
  const int o = lane & 31, half = lane >> 5;

  __shared__ float ub_l[DD], uf_l[DD], e_l[2 * DD];
  __shared__ float label_s[NSTEP];
  __shared__ int skill_s[NSTEP];

  for (int i = lane; i < NSTEP; i += 64) {
    label_s[i] = labels[b * TTOT + i + 1];
    skill_s[i] = skills[b * TTOT + i + 1];
  }

  float w1r[80];
#pragma unroll
  for (int k = 0; k < 8; ++k) {
    const int c0 = (half * 8 + k) * 2;
#pragma unroll
    for (int j = 0; j < 5; ++j) {
      w1r[k * 10 + j] = w1g[o * 160 + c0 * 5 + j];
      w1r[k * 10 + 5 + j] = w1g[o * 160 + (c0 + 1) * 5 + j];
    }
  }
  float w2r[16];
#pragma unroll
  for (int cc = 0; cc < 16; ++cc) w2r[cc] = w2g[o * 32 + half * 16 + cc];
  const float* wsg = half ? wbg : wfg;
  float wsr[32];
#pragma unroll
  for (int c = 0; c < DD; ++c) wsr[c] = wsg[o * 32 + c];
  const float b1r = b1g[o], b2r = b2g[o];
  const float bselr = half ? bbg[o] : bfg[o];

  float val = half ? ub0g[b * DD + o] : uf0g[b * DD + o];

  __syncthreads();

  float* UBp = UBg + (size_t)b * NSTEP * DD;
  float* UFp = UFg + (size_t)b * NSTEP * DD;

  float ev = emb[(size_t)skill_s[0] * (2 * DD) + lane];
  float pg[8];

  for (int step = 0; step < NSTEP; ++step) {
    if (step) {
      float part = 0.f;
#pragma unroll
      for (int s2 = 0; s2 < 8; ++s2) part += pg[s2];
      float h = b1r + part + __shfl_xor(part, 32);
      h = fmaxf(h, 0.f);
      float up = 0.f;
#pragma unroll
      for (int cc = 0; cc < 16; ++cc) {
        float hv0 = rlane(h, cc), hv1 = rlane(h, 16 + cc);
        up += (half ? hv1 : hv0) * w2r[cc];
      }
      float uu = b2r + up + __shfl_xor(up, 32);
      float aac = bselr;
#pragma unroll
      for (int c = 0; c < DD; ++c) aac += rlane(uu, c) * wsr[c];
      val = 1.f - 2.f / (1.f + __expf(2.f * aac));
    }
    if (half) ub_l[o] = val; else uf_l[o] = val;
    e_l[lane] = ev;
    (half ? UBp : UFp)[step * DD + o] = val;
    if (step + 1 < NSTEP) ev = emb[(size_t)skill_s[step + 1] * (2 * DD) + lane];
    const float lab = label_s[step];
#pragma unroll
    for (int k = 0; k < 8; ++k) {
      const int c0 = (half * 8 + k) * 2;
      float ubc0 = ub_l[c0], ubc1 = ub_l[c0 + 1];
      float ufc0 = uf_l[c0], ufc1 = uf_l[c0 + 1];
      float rs0 = e_l[c0], rs1 = e_l[c0 + 1];
      float rr0 = e_l[DD + c0], rr1 = e_l[DD + c0 + 1];
      float hpart = ubc0 * w1r[k * 10 + 0] + ufc0 * w1r[k * 10 + 1] +
                    lab * w1r[k * 10 + 2] + rr0 * w1r[k * 10 + 3] +
                    rs0 * w1r[k * 10 + 4];
      hpart += ubc1 * w1r[k * 10 + 5] + ufc1 * w1r[k * 10 + 6] +
               lab * w1r[k * 10 + 7] + rr1 * w1r[k * 10 + 8] +
               rs1 * w1r[k * 10 + 9];
      pg[k] = hpart;
    }
  }
}

// ---------------------------------------------------------------------------
// P2: NCB/TC precompute (legacy 4-group order exact).
// ---------------------------------------------------------------------------
__global__ __launch_bounds__(512) void precomp_kernel(
    const int* __restrict__ times, const float* __restrict__ emb,
    const float* __restrict__ UBg, const float* __restrict__ UFg,
    float* __restrict__ NCBg, float* __restrict__ TCg) {
  const int b = blockIdx.x;
  const int s0 = blockIdx.y * 8;
  const int n = threadIdx.x;
  float nr[DD], ns[DD];
#pragma unroll
  for (int c = 0; c < DD; ++c) {
    ns[c] = emb[(size_t)n * (2 * DD) + c];
    nr[c] = emb[(size_t)n * (2 * DD) + DD + c];
  }
  for (int s = s0; s < s0 + 8 && s < NSTEP; ++s) {
    const float* ubp = UBg + ((size_t)b * NSTEP + s) * DD;
    const float* ufp = UFg + ((size_t)b * NSTEP + (s ? s - 1 : 0)) * DD;
    float n0 = 0.f, n1 = 0.f, n2 = 0.f, n3 = 0.f;
    float l0 = 0.f, l1 = 0.f, l2 = 0.f, l3 = 0.f;
#pragma unroll
    for (int c = 0; c < 8; ++c) {
      n0 += ubp[c] * nr[c];
      n1 += ubp[8 + c] * nr[8 + c];
      n2 += ubp[16 + c] * nr[16 + c];
      n3 += ubp[24 + c] * nr[24 + c];
      l0 += ufp[c] * ns[c];
      l1 += ufp[8 + c] * ns[8 + c];
      l2 += ufp[16 + c] * ns[16 + c];
      l3 += ufp[24 + c] * ns[24 + c];
    }
    float ncb = (n0 + n1) + (n2 + n3);
    float nlf = (l0 + l1) + (l2 + l3);
    int dt_ = times[b * TTOT + s + 1] - times[b * TTOT + s];
    if (dt_ < 0) dt_ = -dt_;
    float delta = __logf((float)dt_ + 1e-6f) * 0.6213349345596119f;  // 1/ln 5
    float tc = __expf(-delta * 0.1f * nlf);
    NCBg[((size_t)b * NSTEP + s) * NN + n] = ncb;
    TCg[((size_t)b * NSTEP + s) * NN + n] = tc;
  }
}

// ---------------------------------------------------------------------------
// P3: light scan.  NEW vs round-9: __launch_bounds__(512, 1).  The grid is
// only 64 blocks on 256 CUs (blocks never co-reside), so the old (512,2)
// bound bought nothing — it only capped VGPR at 128/wave, below mreg's 128
// fragment registers, forcing per-step global re-loads of the M fragments
// (observed VGPR_Count 124-128).  (512,1) doubles the budget to 256 so mreg
// stays register-resident.  No arithmetic change -> bit-identical output.
// ---------------------------------------------------------------------------
__global__ __launch_bounds__(512, 1) void scan_fast(
    const int* __restrict__ skills, const float* __restrict__ NCBg,
    const float* __restrict__ TCg, const unsigned char* __restrict__ M8k,
    const unsigned char* __restrict__ M8x, int allow_mx,
    const int* __restrict__ flag, float* __restrict__ out) {
  const int b = blockIdx.x;
  const int t = threadIdx.x;
  const int lane = t & 63, w = t >> 6, q = lane >> 4;
  __shared__ __align__(32) unsigned char lp8[2][NN];
  __shared__ int skill_s[NSTEP];
  const int use_mx = allow_mx && (*flag);
  for (int i = t; i < NSTEP; i += 512) skill_s[i] = skills[b * TTOT + i + 1];

  union MU { i32x8 v; long l[4]; };
  MU mreg[16];
  if (use_mx) {
    const unsigned char* Mb = M8x + (size_t)b * NN * NN;
#pragma unroll
    for (int c = 0; c < 4; ++c)
#pragma unroll
      for (int i = 0; i < 4; ++i)
        mreg[c * 4 + i].v = *(const i32x8*)(
            Mb + (((size_t)(c * 32 + w * 4 + i) * 64 + lane) << 5));
  } else {
    const unsigned char* Mb = M8k + (size_t)b * NN * NN;
#pragma unroll
    for (int c = 0; c < 16; ++c)
#pragma unroll
      for (int i = 0; i < 4; ++i)
        mreg[c].l[i] = *(const long*)(
            Mb + (((size_t)(w * 64 + i * 16 + c)) << 9) + (size_t)lane * 8);
  }
  const float* ncbp = NCBg + (size_t)b * NSTEP * NN + t;
  const float* tcp = TCg + (size_t)b * NSTEP * NN + t;
  float ncb_c = ncbp[0];
  float tc_c = tcp[0];
  float ncb_n1 = 0.f, tc_n1 = 1.f;
  if (NSTEP > 1) { ncb_n1 = ncbp[NN]; tc_n1 = tcp[NN]; }
  float rlp = ncb_c;  // lp_0 == ncb_0
  lp8[0][t] = e4m3(rlp);
  __syncthreads();

  int pidx = -1;
  float pval = 0.f;
  for (int step = 0; step < NSTEP; ++step) {
    const int cb = step & 1;
    if (pidx >= 0) out[pidx] = pval;
    // issue prefetch for step+2 (consumed two iterations from now)
    float ncb_n2 = 0.f, tc_n2 = 1.f;
    if (step + 2 < NSTEP) {
      ncb_n2 = ncbp[(size_t)(step + 2) * NN];
      tc_n2 = tcp[(size_t)(step + 2) * NN];
    }
    int sk_s = skill_s[step];
    f32x4 zero = {0.f, 0.f, 0.f, 0.f};
    f32x4 acc[4] = {zero, zero, zero, zero};
    if (use_mx) {
#pragma unroll
      for (int c = 0; c < 4; ++c) {
        i32x8 af = *(const i32x8*)(&lp8[cb][c * 128 + q * 32]);
#pragma unroll
        for (int i = 0; i < 4; ++i)
          acc[i] = __builtin_amdgcn_mfma_scale_f32_16x16x128_f8f6f4(
              af, mreg[c * 4 + i].v, acc[i], 0, 0, 0, 127, 0, 127);
      }
    } else {
#pragma unroll
      for (int c = 0; c < 16; ++c) {
        long af = *(const long*)(&lp8[cb][c * 32 + q * 8]);
#pragma unroll
        for (int i = 0; i < 4; ++i)
          acc[i] = __builtin_amdgcn_mfma_f32_16x16x32_fp8_fp8(af, mreg[c].l[i],
                                                              acc[i], 0, 0, 0);
      }
    }
    float spatial = ((q & 2) ? ((q & 1) ? acc[3][0] : acc[2][0])
                             : ((q & 1) ? acc[1][0] : acc[0][0])) * 0x1p-20f;
    float cur = 1.f / (1.f + __expf(-((ncb_c + tc_c * rlp) + spatial)));
    pidx = (t == sk_s) ? (step * BSZ + b) : -1;
    pval = cur;
    rlp = cur;
    lp8[cb ^ 1][t] = e4m3(cur);
    __syncthreads();
    ncb_c = ncb_n1; tc_c = tc_n1;
    ncb_n1 = ncb_n2; tc_n1 = tc_n2;
  }
  if (pidx >= 0) out[pidx] = pval;
}

// ---------------------------------------------------------------------------
// LEGACY scan — retained verbatim for low-workspace tiers.
// ---------------------------------------------------------------------------
__global__ __launch_bounds__(512, 2) void scan_kernel(
    const int* __restrict__ skills, const int* __restrict__ times,
    const float* __restrict__ labels, const float* __restrict__ emb,
    const float* __restrict__ ub0g, const float* __restrict__ uf0g,
    const float* __restrict__ w1g, const float* __restrict__ b1g,
    const float* __restrict__ w2g, const float* __restrict__ b2g,
    const float* __restrict__ wfg, const float* __restrict__ bfg,
    const float* __restrict__ wbg, const float* __restrict__ bbg,
    const unsigned char* __restrict__ M8k, const unsigned char* __restrict__ M8x,
    int allow_mx, const int* __restrict__ flag, float* __restrict__ out) {
  const int b = blockIdx.x;
  const int t = threadIdx.x;
  const int lane = t & 63, w = t >> 6, q = lane >> 4;

  __shared__ __align__(32) unsigned char lp8[NN];
  __shared__ float ub[DD], uf[DD];
  __shared__ float delta_s[NSTEP], label_s[NSTEP];
  __shared__ int skill_s[NSTEP];
  __shared__ float hp[16][33];
  __shared__ float w1t[DD * 5 * DD];
  __shared__ float w2t[DD * DD], wft[DD * DD], wbt[DD * DD];
  __shared__ float b1s[DD], b2s[DD], bfs[DD], bbs[DD];

  const int use_mx = allow_mx && (*flag);

  float nrec[DD], nsend[DD];
#pragma unroll
  for (int c = 0; c < DD; ++c) {
    nsend[c] = emb[(size_t)t * (2 * DD) + c];
    nrec[c] = emb[(size_t)t * (2 * DD) + DD + c];
  }
  for (int idx = t; idx < DD * DD * 5; idx += 512) {
    int o = idx / 160, rem = idx % 160;
    w1t[rem * 32 + o] = w1g[idx];
  }
  for (int idx = t; idx < DD * DD; idx += 512) {
    int o = idx >> 5, c = idx & 31;
    w2t[c * 32 + o] = w2g[idx];
    wft[c * 32 + o] = wfg[idx];
    wbt[c * 32 + o] = wbg[idx];
  }
  if (t < DD) {
    b1s[t] = b1g[t]; b2s[t] = b2g[t];
    bfs[t] = bfg[t]; bbs[t] = bbg[t];
    ub[t] = ub0g[b * DD + t];
    uf[t] = uf0g[b * DD + t];
  }
  for (int i = t; i < NSTEP; i += 512) {
    int dt_ = times[b * TTOT + i + 1] - times[b * TTOT + i];
    if (dt_ < 0) dt_ = -dt_;
    delta_s[i] = __logf((float)dt_ + 1e-6f) * 0.6213349345596119f;
    label_s[i] = labels[b * TTOT + i + 1];
    skill_s[i] = skills[b * TTOT + i + 1];
  }

  union MU { i32x8 v; long l[4]; };
  MU mreg[16];
  if (use_mx) {
    const unsigned char* Mb = M8x + (size_t)b * NN * NN;
#pragma unroll
    for (int c = 0; c < 4; ++c)
#pragma unroll
      for (int i = 0; i < 4; ++i)
        mreg[c * 4 + i].v = *(const i32x8*)(
            Mb + (((size_t)(c * 32 + w * 4 + i) * 64 + lane) << 5));
  } else {
    const unsigned char* Mb = M8k + (size_t)b * NN * NN;
#pragma unroll
    for (int c = 0; c < 16; ++c)
#pragma unroll
      for (int i = 0; i < 4; ++i)
        mreg[c].l[i] = *(const long*)(
            Mb + (((size_t)(w * 64 + i * 16 + c)) << 9) + (size_t)lane * 8);
  }
  __syncthreads();

  float rlp = 0.f, rnlf = 0.f;
#pragma unroll
  for (int c = 0; c < DD; ++c) {
    rlp += ub[c] * nrec[c];
    rnlf += uf[c] * nsend[c];
  }
  lp8[t] = e4m3(rlp);
  __syncthreads();

  for (int step = 0; step < NSTEP; ++step) {
    if (step && w == 0) {
      int o = lane & 31, half = lane >> 5;
      float part = 0.f;
#pragma unroll
      for (int s2 = 0; s2 < 8; ++s2) part += hp[half * 8 + s2][o];
      float h = b1s[o] + part + __shfl_xor(part, 32);
      h = fmaxf(h, 0.f);
      float up = 0.f;
#pragma unroll
      for (int cc = 0; cc < 16; ++cc) {
        float hv0 = rlane(h, cc), hv1 = rlane(h, 16 + cc);
        up += (half ? hv1 : hv0) * w2t[(half * 16 + cc) * 32 + o];
      }
      float uu = b2s[o] + up + __shfl_xor(up, 32);
      const float* wsel = half ? wbt : wft;
      float aac = half ? bbs[o] : bfs[o];
#pragma unroll
      for (int c = 0; c < DD; ++c) aac += rlane(uu, c) * wsel[c * 32 + o];
      float val = 1.f - 2.f / (1.f + __expf(2.f * aac));
      if (half) ub[o] = val;
      else uf[o] = val;
    }
    f32x4 zero = {0.f, 0.f, 0.f, 0.f};
    f32x4 acc[4] = {zero, zero, zero, zero};
    if (use_mx) {
#pragma unroll
      for (int c = 0; c < 4; ++c) {
        i32x8 af = *(const i32x8*)(&lp8[c * 128 + q * 32]);
#pragma unroll
        for (int i = 0; i < 4; ++i)
          acc[i] = __builtin_amdgcn_mfma_scale_f32_16x16x128_f8f6f4(
              af, mreg[c * 4 + i].v, acc[i], 0, 0, 0, 127, 0, 127);
      }
    } else {
#pragma unroll
      for (int c = 0; c < 16; ++c) {
        long af = *(const long*)(&lp8[c * 32 + q * 8]);
#pragma unroll
        for (int i = 0; i < 4; ++i)
          acc[i] = __builtin_amdgcn_mfma_f32_16x16x32_fp8_fp8(af, mreg[c].l[i],
                                                              acc[i], 0, 0, 0);
      }
    }
    float spatial = ((q & 2) ? ((q & 1) ? acc[3][0] : acc[2][0])
                             : ((q & 1) ? acc[1][0] : acc[0][0])) * 0x1p-20f;
    __syncthreads();

    float rub = ub[lane & 31], ruf = uf[lane & 31];
    float n0 = 0.f, n1 = 0.f, n2 = 0.f, n3 = 0.f;
    float l0 = 0.f, l1 = 0.f, l2 = 0.f, l3 = 0.f;
#pragma unroll
    for (int c = 0; c < 8; ++c) {
      n0 += rlane(rub, c) * nrec[c];
      n1 += rlane(rub, 8 + c) * nrec[8 + c];
      n2 += rlane(rub, 16 + c) * nrec[16 + c];
      n3 += rlane(rub, 24 + c) * nrec[24 + c];
      l0 += rlane(ruf, c) * nsend[c];
      l1 += rlane(ruf, 8 + c) * nsend[8 + c];
      l2 += rlane(ruf, 16 + c) * nsend[16 + c];
      l3 += rlane(ruf, 24 + c) * nsend[24 + c];
    }
    float ncb = (n0 + n1) + (n2 + n3);
    float nlfn = (l0 + l1) + (l2 + l3);
    float e = __expf(-delta_s[step] * 0.1f * rnlf) * rlp;
    float cur = 1.f / (1.f + __expf(-(ncb + e + spatial)));

    {
      int o = t & 31, s = t >> 5;
      float lab = label_s[step];
      int sk = skill_s[step];
      float hpart = 0.f;
#pragma unroll
      for (int cc = 0; cc < 2; ++cc) {
        int c = (s << 1) + cc;
        const float* wrow = &w1t[(c * 5) * 32 + o];
        float rs = emb[(size_t)sk * (2 * DD) + c];
        float rr = emb[(size_t)sk * (2 * DD) + DD + c];
        hpart += ub[c] * wrow[0] + uf[c] * wrow[32] + lab * wrow[64] +
                 rr * wrow[96] + rs * wrow[128];
      }
      hp[s][o] = hpart;
    }

    rlp = cur;
    rnlf = nlfn;
    lp8[t] = e4m3(cur);
    if (t == skill_s[step]) out[step * BSZ + b] = cur;
    __syncthreads();
  }
}

extern "C" void kernel_launch(void* const* d_in, const int* in_sizes, int n_in,
                              void* d_out, int out_size, void* d_ws, size_t ws_size,
                              hipStream_t stream) {
  (void)in_sizes; (void)n_in; (void)out_size;
  const int* skills = (const int*)d_in[0];
  const int* times = (const int*)d_in[1];
  const float* labels = (const float*)d_in[2];
  const float* adj = (const float*)d_in[3];
  const float* emb = (const float*)d_in[4];
  const float* ub0 = (const float*)d_in[5];
  const float* uf0 = (const float*)d_in[6];
  const float* w1 = (const float*)d_in[7];
  const float* b1 = (const float*)d_in[8];
  const float* w2 = (const float*)d_in[9];
  const float* b2 = (const float*)d_in[10];
  const float* wf = (const float*)d_in[11];
  const float* bf = (const float*)d_in[12];
  const float* wb = (const float*)d_in[13];
  const float* bb = (const float*)d_in[14];

  const size_t mat = (size_t)BSZ * NN * NN;                        // 16,777,216
  const size_t ncb_sz = (size_t)BSZ * NSTEP * NN * sizeof(float);  // 26,083,328
  const size_t ub_sz = (size_t)BSZ * NSTEP * DD * sizeof(float);   //  1,630,208
  char* base = (char*)d_ws;
  unsigned char *M8k, *M8x;
  unsigned short *A2, *A1T = nullptr;
  char* ovl = nullptr;  // A2+A1T region, dead after gemm_m -> NCB/TC/UB/UF
  int* flag;
  int use_fast, allow_mx;
  if (ws_size >= 6 * mat + 4) {          // fast gemms + MX
    use_fast = 1; allow_mx = 1;
    M8k = (unsigned char*)base; M8x = M8k + mat;
    A2 = (unsigned short*)(base + 2 * mat);
    A1T = (unsigned short*)(base + 4 * mat);
    flag = (int*)(base + 6 * mat);
    ovl = base + 2 * mat;                // 67.1 MB >= 55.4 MB needed
  } else if (ws_size >= 5 * mat + 4) {   // fast gemms, no MX
    use_fast = 1; allow_mx = 0;
    M8k = (unsigned char*)base; M8x = M8k;
    A2 = (unsigned short*)(base + mat);
    A1T = (unsigned short*)(base + 3 * mat);
    flag = (int*)(base + 5 * mat);
    ovl = base + mat;
  } else if (ws_size >= 4 * mat + 4) {   // slow gemms + MX (legacy scan)
    use_fast = 0; allow_mx = 1;
    M8k = (unsigned char*)base; M8x = M8k + mat;
    A2 = (unsigned short*)(base + 2 * mat);
    flag = (int*)(base + 4 * mat);
  } else {                               // slow, no MX (legacy scan)
    use_fast = 0; allow_mx = 0;
    M8k = (unsigned char*)base; M8x = M8k;
    A2 = (unsigned short*)(base + mat);
    flag = (int*)(base + 3 * mat);
  }

  dim3 gb(256);
  if (use_fast) {
    dim3 gt(8, 8, BSZ);   // transpose: 64-tiles
    dim3 gf(4, 4, BSZ);   // staged gemms: 128-tiles, batch-adjacent
    transpose_kernel<<<gt, gb, 0, stream>>>(adj, A1T);
    gemm_a2_fast<<<gf, gb, 0, stream>>>(adj, A1T, A2);
    gemm_m_fast<<<gf, gb, 0, stream>>>(adj, A1T, A2, M8k, M8x, allow_mx);
    float* NCB = (float*)ovl;
    float* TC = (float*)(ovl + ncb_sz);
    float* UB = (float*)(ovl + 2 * ncb_sz);
    float* UF = (float*)(ovl + 2 * ncb_sz + ub_sz);
    traj2_kernel<<<dim3(BSZ), dim3(64), 0, stream>>>(
        skills, labels, emb, ub0, uf0, w1, b1, w2, b2, wf, bf, wb, bb, UB, UF);
    precomp_kernel<<<dim3(BSZ, 25), dim3(512), 0, stream>>>(times, emb, UB, UF,
                                                            NCB, TC);
    probe_kernel<<<dim3(1), dim3(64), 0, stream>>>(flag);
    scan_fast<<<dim3(BSZ), dim3(512), 0, stream>>>(skills, NCB, TC, M8k, M8x,
                                                   allow_mx, flag, (float*)d_out);
  } else {
    dim3 gg(BSZ, 8, 8);
    gemm_a2_slow<<<gg, gb, 0, stream>>>(adj, A2);
    gemm_m_slow<<<gg, gb, 0, stream>>>(adj, A2, M8k, M8x, allow_mx);
    probe_kernel<<<dim3(1), dim3(64), 0, stream>>>(flag);
    scan_kernel<<<dim3(BSZ), dim3(512), 0, stream>>>(
        skills, times, labels, emb, ub0, uf0, w1, b1, w2, b2, wf, bf, wb, bb,
        M8k, M8x, allow_mx, flag, (float*)d_out);
  }
}

// Round 12
// 639.435 us; speedup vs baseline: 1.0617x; 1.0160x over previous
//
#include <hip/hip_runtime.h>

#define NN 512
#define BSZ 64
#define TTOT 200
#define NSTEP 199
#define DD 32

typedef __attribute__((ext_vector_type(8))) short bf16x8;
typedef __attribute__((ext_vector_type(8))) int i32x8;
typedef __attribute__((ext_vector_type(4))) float f32x4;
typedef __attribute__((ext_vector_type(4))) unsigned int u32x4;

__device__ __forceinline__ float bf2f(unsigned short u) {
  union { unsigned int i; float f; } v; v.i = ((unsigned int)u) << 16; return v.f;
}
__device__ __forceinline__ unsigned short f2bf(float f) {  // RNE
  unsigned int b = __float_as_uint(f);
  return (unsigned short)((b + 0x7fffu + ((b >> 16) & 1u)) >> 16);
}
__device__ __forceinline__ unsigned int pk_trunc(float hi, float lo) {
  return __builtin_amdgcn_perm(__float_as_uint(hi), __float_as_uint(lo), 0x07060302u);
}
// f32 -> OCP e4m3 (RNE on normals; flush tiny to 0; clamp 448)
__device__ __forceinline__ unsigned char e4m3(float x) {
  float a = fabsf(x);
  unsigned int s = (__float_as_uint(x) >> 24) & 0x80u;
  if (a < 0.01171875f) return (unsigned char)s;
  a = fminf(a, 448.0f);
  unsigned int u = __float_as_uint(a);
  unsigned int keep = (u >> 20) & 7u;
  unsigned int rest = u & 0xFFFFFu;
  unsigned int base = (((u >> 23) - 120u) << 3) | keep;
  unsigned int rnd = (rest > 0x80000u) || (rest == 0x80000u && (keep & 1u));
  return (unsigned char)(s | (base + rnd));
}
__device__ __forceinline__ float dec8(unsigned char x) {  // e4m3 -> f32
  int e = (x >> 3) & 15, m = x & 7;
  float v = e ? ldexpf(8.f + (float)m, e - 10) : ldexpf((float)m, -9);
  return (x & 0x80) ? -v : v;
}
__device__ __forceinline__ float rlane(float v, int l) {
  return __int_as_float(__builtin_amdgcn_readlane(__float_as_int(v), l));
}

// K=32 fp8 B-frag layout (round-4 HW-PROVEN)
__device__ __forceinline__ size_t m8_addr(int k, int col) {
  int nt = col >> 4, cch = k >> 5;
  int l2 = (((k >> 3) & 3) << 4) + (col & 15);
  return (size_t)((nt * 16 + cch) * 512) + (size_t)l2 * 8 + (size_t)(k & 7);
}
// K=128 MX B-frag layout (probe-verified)
__device__ __forceinline__ size_t m8mxa(int k, int col) {
  int f = ((k >> 7) << 5) + (col >> 4);
  int ln2 = (((k >> 5) & 3) << 4) + (col & 15);
  return (((size_t)f * 64 + ln2) << 5) + (size_t)(k & 31);
}

// ---------------------------------------------------------------------------
// GEMM 1 fast (LDS-staged): A2 = A1@A1, bf16 out.  128x128 tile, BK=64,
// 4 waves (2x2).  NEW: B-operand transposed+truncated ON THE FLY from A1
// (same pk_trunc pairing, same granule layout, same swizzled slots as the
// old A1T path -> bit-identical MFMA inputs).  transpose_kernel + the A1T
// buffer round-trip are eliminated.
// ---------------------------------------------------------------------------
__global__ __launch_bounds__(256) void gemm_a2_fast(
    const float* __restrict__ A1, unsigned short* __restrict__ A2) {
  const int tn = blockIdx.x, tm = blockIdx.y, b = blockIdx.z;
  const int tid = threadIdx.x, lane = tid & 63;
  const int w = tid >> 6, wr = w >> 1, wc = w & 1;
  const int q = lane >> 4, ln = lane & 15;
  const size_t Ao = (size_t)b * NN * NN;
  __shared__ __align__(16) unsigned char Asw[128 * 128];
  __shared__ __align__(16) unsigned char Bsw[128 * 128];
  f32x4 acc[4][4];
#pragma unroll
  for (int mi = 0; mi < 4; ++mi)
#pragma unroll
    for (int ni = 0; ni < 4; ++ni) acc[mi][ni] = f32x4{0.f, 0.f, 0.f, 0.f};

  const int arow = tid >> 2, achk = tid & 3;
  const int bg = tid >> 5, bc0 = (tid & 31) * 4;  // B: granule 0..7, 4 cols
  const float* Ab = A1 + Ao;

  for (int k0 = 0; k0 < NN; k0 += 64) {
    // stage A: f32 -> trunc bf16 rows (verbatim)
#pragma unroll
    for (int p = 0; p < 2; ++p) {
      const int r = arow + p * 64;
      const float* src = Ab + (size_t)(tm * 128 + r) * NN + k0 + achk * 16;
      f32x4 x0 = *(const f32x4*)src, x1 = *(const f32x4*)(src + 4);
      f32x4 x2 = *(const f32x4*)(src + 8), x3 = *(const f32x4*)(src + 12);
      u32x4 y0 = u32x4{pk_trunc(x0[1], x0[0]), pk_trunc(x0[3], x0[2]),
                       pk_trunc(x1[1], x1[0]), pk_trunc(x1[3], x1[2])};
      u32x4 y1 = u32x4{pk_trunc(x2[1], x2[0]), pk_trunc(x2[3], x2[2]),
                       pk_trunc(x3[1], x3[0]), pk_trunc(x3[3], x3[2])};
      const int sw = r & 7;
      *(u32x4*)(Asw + r * 128 + (((achk * 2) ^ sw) << 4)) = y0;
      *(u32x4*)(Asw + r * 128 + (((achk * 2 + 1) ^ sw) << 4)) = y1;
    }
    // stage B: on-the-fly transpose+trunc of A1 rows k0+8g..+8, cols tn*128+
    {
      f32x4 r[8];
#pragma unroll
      for (int i = 0; i < 8; ++i)
        r[i] = *(const f32x4*)(Ab + (size_t)(k0 + bg * 8 + i) * NN + tn * 128 + bc0);
#pragma unroll
      for (int m = 0; m < 4; ++m) {
        const int col = bc0 + m;
        u32x4 v = u32x4{pk_trunc(r[1][m], r[0][m]), pk_trunc(r[3][m], r[2][m]),
                        pk_trunc(r[5][m], r[4][m]), pk_trunc(r[7][m], r[6][m])};
        *(u32x4*)(Bsw + col * 128 + ((bg ^ (col & 7)) << 4)) = v;
      }
    }
    __syncthreads();
#pragma unroll
    for (int ks = 0; ks < 2; ++ks) {
      bf16x8 af[4], bv[4];
#pragma unroll
      for (int mi = 0; mi < 4; ++mi) {
        const int r = wr * 64 + mi * 16 + ln;
        af[mi] = *(const bf16x8*)(Asw + r * 128 + (((ks * 4 + q) ^ (r & 7)) << 4));
      }
#pragma unroll
      for (int ni = 0; ni < 4; ++ni) {
        const int r = wc * 64 + ni * 16 + ln;
        bv[ni] = *(const bf16x8*)(Bsw + r * 128 + (((ks * 4 + q) ^ (r & 7)) << 4));
      }
#pragma unroll
      for (int mi = 0; mi < 4; ++mi)
#pragma unroll
        for (int ni = 0; ni < 4; ++ni)
          acc[mi][ni] = __builtin_amdgcn_mfma_f32_16x16x32_bf16(
              af[mi], bv[ni], acc[mi][ni], 0, 0, 0);
    }
    __syncthreads();
  }
  unsigned short* Cb = A2 + Ao;
#pragma unroll
  for (int mi = 0; mi < 4; ++mi)
#pragma unroll
    for (int ni = 0; ni < 4; ++ni) {
      const int col = tn * 128 + wc * 64 + ni * 16 + ln;
#pragma unroll
      for (int r = 0; r < 4; ++r) {
        const int row = tm * 128 + wr * 64 + mi * 16 + q * 4 + r;
        Cb[(size_t)row * NN + col] = f2bf(acc[mi][ni][r]);
      }
    }
}

// ---------------------------------------------------------------------------
// GEMM 2 fast (LDS-staged): A3 = A2@A1; M*2^20 -> e4m3 dual layouts.
// Same on-the-fly B transpose as gemm_a2_fast (bit-identical values).
// ---------------------------------------------------------------------------
__global__ __launch_bounds__(256) void gemm_m_fast(
    const float* __restrict__ A1, const unsigned short* __restrict__ A2,
    unsigned char* __restrict__ M8k, unsigned char* __restrict__ M8x,
    int has_mx) {
  const int tn = blockIdx.x, tm = blockIdx.y, b = blockIdx.z;
  const int tid = threadIdx.x, lane = tid & 63;
  const int w = tid >> 6, wr = w >> 1, wc = w & 1;
  const int q = lane >> 4, ln = lane & 15;
  const size_t Ao = (size_t)b * NN * NN;
  __shared__ __align__(16) unsigned char Asw[128 * 128];
  __shared__ __align__(16) unsigned char Bsw[128 * 128];
  f32x4 acc[4][4];
#pragma unroll
  for (int mi = 0; mi < 4; ++mi)
#pragma unroll
    for (int ni = 0; ni < 4; ++ni) acc[mi][ni] = f32x4{0.f, 0.f, 0.f, 0.f};

  const int srow = tid >> 1, sh = tid & 1;
  const int bg = tid >> 5, bc0 = (tid & 31) * 4;
  const unsigned short* A2b = A2 + Ao;
  const float* Ab = A1 + Ao;

  for (int k0 = 0; k0 < NN; k0 += 64) {
    // stage A: bf16 copy of A2 rows (verbatim)
    {
      const unsigned short* asrc = A2b + (size_t)(tm * 128 + srow) * NN + k0 + sh * 32;
      const int sw = srow & 7;
#pragma unroll
      for (int j = 0; j < 4; ++j) {
        u32x4 va = *(const u32x4*)(asrc + j * 8);
        *(u32x4*)(Asw + srow * 128 + (((sh * 4 + j) ^ sw) << 4)) = va;
      }
    }
    // stage B: on-the-fly transpose+trunc of A1
    {
      f32x4 r[8];
#pragma unroll
      for (int i = 0; i < 8; ++i)
        r[i] = *(const f32x4*)(Ab + (size_t)(k0 + bg * 8 + i) * NN + tn * 128 + bc0);
#pragma unroll
      for (int m = 0; m < 4; ++m) {
        const int col = bc0 + m;
        u32x4 v = u32x4{pk_trunc(r[1][m], r[0][m]), pk_trunc(r[3][m], r[2][m]),
                        pk_trunc(r[5][m], r[4][m]), pk_trunc(r[7][m], r[6][m])};
        *(u32x4*)(Bsw + col * 128 + ((bg ^ (col & 7)) << 4)) = v;
      }
    }
    __syncthreads();
#pragma unroll
    for (int ks = 0; ks < 2; ++ks) {
      bf16x8 af[4], bv[4];
#pragma unroll
      for (int mi = 0; mi < 4; ++mi) {
        const int r = wr * 64 + mi * 16 + ln;
        af[mi] = *(const bf16x8*)(Asw + r * 128 + (((ks * 4 + q) ^ (r & 7)) << 4));
      }
#pragma unroll
      for (int ni = 0; ni < 4; ++ni) {
        const int r = wc * 64 + ni * 16 + ln;
        bv[ni] = *(const bf16x8*)(Bsw + r * 128 + (((ks * 4 + q) ^ (r & 7)) << 4));
      }
#pragma unroll
      for (int mi = 0; mi < 4; ++mi)
#pragma unroll
        for (int ni = 0; ni < 4; ++ni)
          acc[mi][ni] = __builtin_amdgcn_mfma_f32_16x16x32_bf16(
              af[mi], bv[ni], acc[mi][ni], 0, 0, 0);
    }
    __syncthreads();
  }
  const float c1 = 1048576.f / (3.f * 512.f * 512.f);
  const float c2 = c1 / 512.f;
  const float c3 = c2 / 512.f;
  unsigned char* Mk = M8k + Ao;
  unsigned char* Mx = M8x + Ao;
#pragma unroll
  for (int mi = 0; mi < 4; ++mi) {
    const int row0 = tm * 128 + wr * 64 + mi * 16 + q * 4;
#pragma unroll
    for (int ni = 0; ni < 4; ++ni) {
      const int col = tn * 128 + wc * 64 + ni * 16 + ln;
      unsigned int wv = 0;
#pragma unroll
      for (int r = 0; r < 4; ++r) {
        const int row = row0 + r;
        float mval = c1 * A1[Ao + (size_t)row * NN + col] +
                     c2 * bf2f(A2b[(size_t)row * NN + col]) + c3 * acc[mi][ni][r];
        wv |= ((unsigned int)e4m3(mval)) << (8 * r);
      }
      *(unsigned int*)(Mk + m8_addr(row0, col)) = wv;
      if (has_mx) *(unsigned int*)(Mx + m8mxa(row0, col)) = wv;
    }
  }
}

// ---------------------------------------------------------------------------
// Slow GEMMs (fallback path; legacy layout, packed stores).
// ---------------------------------------------------------------------------
__global__ __launch_bounds__(256) void gemm_a2_slow(
    const float* __restrict__ A1, unsigned short* __restrict__ A2) {
  const int b = blockIdx.x, tn = blockIdx.y, tm = blockIdx.z;
  const int tid = threadIdx.x, lane = tid & 63, w = tid >> 6;
  const int q = lane >> 4, ln = lane & 15;
  const size_t Ao = (size_t)b * NN * NN;
  f32x4 zero = {0.f, 0.f, 0.f, 0.f};
  f32x4 acc[4] = {zero, zero, zero, zero};
  const float* ap = A1 + Ao + (size_t)(tm * 64 + w * 16 + ln) * NN + q * 8;
  for (int k0 = 0; k0 < NN; k0 += 32) {
    f32x4 x0 = *(const f32x4*)(ap + k0);
    f32x4 x1 = *(const f32x4*)(ap + k0 + 4);
    union { bf16x8 v; unsigned int u[4]; } af;
    af.u[0] = pk_trunc(x0[1], x0[0]);
    af.u[1] = pk_trunc(x0[3], x0[2]);
    af.u[2] = pk_trunc(x1[1], x1[0]);
    af.u[3] = pk_trunc(x1[3], x1[2]);
#pragma unroll
    for (int i = 0; i < 4; ++i) {
      bf16x8 bv;
#pragma unroll
      for (int j = 0; j < 8; ++j)
        bv[j] = (short)f2bf(A1[Ao + (size_t)(k0 + q * 8 + j) * NN + tn * 64 + i * 16 + ln]);
      acc[i] = __builtin_amdgcn_mfma_f32_16x16x32_bf16(af.v, bv, acc[i], 0, 0, 0);
    }
  }
  unsigned short* Cb = A2 + Ao;
#pragma unroll
  for (int i = 0; i < 4; ++i) {
    int col = tn * 64 + i * 16 + ln;
#pragma unroll
    for (int r = 0; r < 4; ++r) {
      int row = tm * 64 + w * 16 + q * 4 + r;
      Cb[(size_t)row * NN + col] = f2bf(acc[i][r]);
    }
  }
}

__global__ __launch_bounds__(256) void gemm_m_slow(
    const float* __restrict__ A1, const unsigned short* __restrict__ A2,
    unsigned char* __restrict__ M8k, unsigned char* __restrict__ M8x,
    int has_mx) {
  const int b = blockIdx.x, tn = blockIdx.y, tm = blockIdx.z;
  const int tid = threadIdx.x, lane = tid & 63, w = tid >> 6;
  const int q = lane >> 4, ln = lane & 15;
  const size_t Ao = (size_t)b * NN * NN;
  const unsigned short* A2b = A2 + Ao;
  f32x4 zero = {0.f, 0.f, 0.f, 0.f};
  f32x4 acc[4] = {zero, zero, zero, zero};
  const unsigned short* ap = A2b + (size_t)(tm * 64 + w * 16 + ln) * NN + q * 8;
  for (int k0 = 0; k0 < NN; k0 += 32) {
    bf16x8 af = *(const bf16x8*)(ap + k0);
#pragma unroll
    for (int i = 0; i < 4; ++i) {
      bf16x8 bv;
#pragma unroll
      for (int j = 0; j < 8; ++j)
        bv[j] = (short)f2bf(A1[Ao + (size_t)(k0 + q * 8 + j) * NN + tn * 64 + i * 16 + ln]);
      acc[i] = __builtin_amdgcn_mfma_f32_16x16x32_bf16(af, bv, acc[i], 0, 0, 0);
    }
  }
  const float c1 = 1048576.f / (3.f * 512.f * 512.f);
  const float c2 = c1 / 512.f;
  const float c3 = c2 / 512.f;
  unsigned char* Mk = M8k + Ao;
  unsigned char* Mx = M8x + Ao;
  const int row0 = tm * 64 + w * 16 + q * 4;
#pragma unroll
  for (int i = 0; i < 4; ++i) {
    int col = tn * 64 + i * 16 + ln;
    unsigned int wv = 0;
#pragma unroll
    for (int r = 0; r < 4; ++r) {
      int row = row0 + r;
      float mval = c1 * A1[Ao + (size_t)row * NN + col] +
                   c2 * bf2f(A2b[(size_t)row * NN + col]) + c3 * acc[i][r];
      wv |= ((unsigned int)e4m3(mval)) << (8 * r);
    }
    *(unsigned int*)(Mk + m8_addr(row0, col)) = wv;
    if (has_mx) *(unsigned int*)(Mx + m8mxa(row0, col)) = wv;
  }
}

// ---------------------------------------------------------------------------
// Probe: HW-verify the assumed K=128 MX layout + scale semantics.
// ---------------------------------------------------------------------------
__global__ __launch_bounds__(64) void probe_kernel(int* __restrict__ flag) {
  const int lane = threadIdx.x, q = lane >> 4, n = lane & 15;
  __shared__ unsigned char A8[128];
  __shared__ unsigned char B8[128 * 16];
  for (int k = lane; k < 128; k += 64) A8[k] = (unsigned char)(8 + ((k * 37 + 11) % 56));
  for (int i = lane; i < 2048; i += 64)
    B8[i] = (unsigned char)(((i & 1) ? 0x80 : 0) | (8 + ((i * 23 + 5) % 56)));
  __syncthreads();
  union { i32x8 v; unsigned char b[32]; } af, bf;
#pragma unroll
  for (int j = 0; j < 32; ++j) {
    af.b[j] = A8[q * 32 + j];
    bf.b[j] = B8[(q * 32 + j) * 16 + n];
  }
  f32x4 acc = {0.f, 0.f, 0.f, 0.f};
  acc = __builtin_amdgcn_mfma_scale_f32_16x16x128_f8f6f4(af.v, bf.v, acc, 0, 0,
                                                         0, 127, 0, 127);
  float ref = 0.f;
  for (int k = 0; k < 128; ++k) ref += dec8(A8[k]) * dec8(B8[k * 16 + n]);
  int ok = 1;
#pragma unroll
  for (int r = 0; r < 4; ++r)
    ok &= (fabsf(acc[r] - ref) <= 1e-3f * fmaxf(fabsf(ref), 1.f)) ? 1 : 0;
  unsigned long long bal = __ballot(ok);
  if (lane == 0) *flag = (bal == ~0ull) ? 1 : 0;
}

// ---------------------------------------------------------------------------
// traj2: ONE WAVE PER BATCH CHAIN, zero barriers in the step loop.
// (round-3/4/9/11 PROVEN at ~169 us — verbatim; do not touch.)
// ---------------------------------------------------------------------------
__global__ __launch_bounds__(64) void traj2_kernel(
    const int* __restrict__ skills, const float* __restrict__ labels,
    const float* __restrict__ emb, const float* __restrict__ ub0g,
    const float* __restrict__ uf0g, const float* __restrict__ w1g,
    const float* __restrict__ b1g, const float* __restrict__ w2g,
    const float* __restrict__ b2g, const float* __restrict__ wfg,
    const float* __restrict__ bfg, const float* __restrict__ wbg,
    const float* __restrict__ bbg, float* __restrict__ UBg,
    float* __restrict__ UFg) {
  const int b = blockIdx.x;
  const int lane = threadIdx.x;
  const int o = lane & 31, half = lane >> 5;

  __shared__ float ub_l[DD], uf_l[DD], e_l[2 * DD];
  __shared__ float label_s[NSTEP];
  __shared__ int skill_s[NSTEP];

  for (int i = lane; i < NSTEP; i += 64) {
    label_s[i] = labels[b * TTOT + i + 1];
    skill_s[i] = skills[b * TTOT + i + 1];
  }

  float w1r[80];
#pragma unroll
  for (int k = 0; k < 8; ++k) {
    const int c0 = (half * 8 + k) * 2;
#pragma unroll
    for (int j = 0; j < 5; ++j) {
      w1r[k * 10 + j] = w1g[o * 160 + c0 * 5 + j];
      w1r[k * 10 + 5 + j] = w1g[o * 160 + (c0 + 1) * 5 + j];
    }
  }
  float w2r[16];
#pragma unroll
  for (int cc = 0; cc < 16; ++cc) w2r[cc] = w2g[o * 32 + half * 16 + cc];
  const float* wsg = half ? wbg : wfg;
  float wsr[32];
#pragma unroll
  for (int c = 0; c < DD; ++c) wsr[c] = wsg[o * 32 + c];
  const float b1r = b1g[o], b2r = b2g[o];
  const float bselr = half ? bbg[o] : bfg[o];

  float val = half ? ub0g[b * DD + o] : uf0g[b * DD + o];

  __syncthreads();

  float* UBp = UBg + (size_t)b * NSTEP * DD;
  float* UFp = UFg + (size_t)b * NSTEP * DD;

  float ev = emb[(size_t)skill_s[0] * (2 * DD) + lane];
  float pg[8];

  for (int step = 0; step < NSTEP; ++step) {
    if (step) {
      float part = 0.f;
#pragma unroll
      for (int s2 = 0; s2 < 8; ++s2) part += pg[s2];
      float h = b1r + part + __shfl_xor(part, 32);
      h = fmaxf(h, 0.f);
      float up = 0.f;
#pragma unroll
      for (int cc = 0; cc < 16; ++cc) {
        float hv0 = rlane(h, cc), hv1 = rlane(h, 16 + cc);
        up += (half ? hv1 : hv0) * w2r[cc];
      }
      float uu = b2r + up + __shfl_xor(up, 32);
      float aac = bselr;
#pragma unroll
      for (int c = 0; c < DD; ++c) aac += rlane(uu, c) * wsr[c];
      val = 1.f - 2.f / (1.f + __expf(2.f * aac));
    }
    if (half) ub_l[o] = val; else uf_l[o] = val;
    e_l[lane] = ev;
    (half ? UBp : UFp)[step * DD + o] = val;
    if (step + 1 < NSTEP) ev = emb[(size_t)skill_s[step + 1] * (2 * DD) + lane];
    const float lab = label_s[step];
#pragma unroll
    for (int k = 0; k < 8; ++k) {
      const int c0 = (half * 8 + k) * 2;
      float ubc0 = ub_l[c0], ubc1 = ub_l[c0 + 1];
      float ufc0 = uf_l[c0], ufc1 = uf_l[c0 + 1];
      float rs0 = e_l[c0], rs1 = e_l[c0 + 1];
      float rr0 = e_l[DD + c0], rr1 = e_l[DD + c0 + 1];
      float hpart = ubc0 * w1r[k * 10 + 0] + ufc0 * w1r[k * 10 + 1] +
                    lab * w1r[k * 10 + 2] + rr0 * w1r[k * 10 + 3] +
                    rs0 * w1r[k * 10 + 4];
      hpart += ubc1 * w1r[k * 10 + 5] + ufc1 * w1r[k * 10 + 6] +
               lab * w1r[k * 10 + 7] + rr1 * w1r[k * 10 + 8] +
               rs1 * w1r[k * 10 + 9];
      pg[k] = hpart;
    }
  }
}

// ---------------------------------------------------------------------------
// P2: NCB/TC precompute (legacy 4-group order exact).
// ---------------------------------------------------------------------------
__global__ __launch_bounds__(512) void precomp_kernel(
    const int* __restrict__ times, const float* __restrict__ emb,
    const float* __restrict__ UBg, const float* __restrict__ UFg,
    float* __restrict__ NCBg, float* __restrict__ TCg) {
  const int b = blockIdx.x;
  const int s0 = blockIdx.y * 8;
  const int n = threadIdx.x;
  float nr[DD], ns[DD];
#pragma unroll
  for (int c = 0; c < DD; ++c) {
    ns[c] = emb[(size_t)n * (2 * DD) + c];
    nr[c] = emb[(size_t)n * (2 * DD) + DD + c];
  }
  for (int s = s0; s < s0 + 8 && s < NSTEP; ++s) {
    const float* ubp = UBg + ((size_t)b * NSTEP + s) * DD;
    const float* ufp = UFg + ((size_t)b * NSTEP + (s ? s - 1 : 0)) * DD;
    float n0 = 0.f, n1 = 0.f, n2 = 0.f, n3 = 0.f;
    float l0 = 0.f, l1 = 0.f, l2 = 0.f, l3 = 0.f;
#pragma unroll
    for (int c = 0; c < 8; ++c) {
      n0 += ubp[c] * nr[c];
      n1 += ubp[8 + c] * nr[8 + c];
      n2 += ubp[16 + c] * nr[16 + c];
      n3 += ubp[24 + c] * nr[24 + c];
      l0 += ufp[c] * ns[c];
      l1 += ufp[8 + c] * ns[8 + c];
      l2 += ufp[16 + c] * ns[16 + c];
      l3 += ufp[24 + c] * ns[24 + c];
    }
    float ncb = (n0 + n1) + (n2 + n3);
    float nlf = (l0 + l1) + (l2 + l3);
    int dt_ = times[b * TTOT + s + 1] - times[b * TTOT + s];
    if (dt_ < 0) dt_ = -dt_;
    float delta = __logf((float)dt_ + 1e-6f) * 0.6213349345596119f;  // 1/ln 5
    float tc = __expf(-delta * 0.1f * nlf);
    NCBg[((size_t)b * NSTEP + s) * NN + n] = ncb;
    TCg[((size_t)b * NSTEP + s) * NN + n] = tc;
  }
}

// ---------------------------------------------------------------------------
// P3: light scan (round-11 config: (512,1), 2-step NCB/TC prefetch).
// ---------------------------------------------------------------------------
__global__ __launch_bounds__(512, 1) void scan_fast(
    const int* __restrict__ skills, const float* __restrict__ NCBg,
    const float* __restrict__ TCg, const unsigned char* __restrict__ M8k,
    const unsigned char* __restrict__ M8x, int allow_mx,
    const int* __restrict__ flag, float* __restrict__ out) {
  const int b = blockIdx.x;
  const int t = threadIdx.x;
  const int lane = t & 63, w = t >> 6, q = lane >> 4;
  __shared__ __align__(32) unsigned char lp8[2][NN];
  __shared__ int skill_s[NSTEP];
  const int use_mx = allow_mx && (*flag);
  for (int i = t; i < NSTEP; i += 512) skill_s[i] = skills[b * TTOT + i + 1];

  union MU { i32x8 v; long l[4]; };
  MU mreg[16];
  if (use_mx) {
    const unsigned char* Mb = M8x + (size_t)b * NN * NN;
#pragma unroll
    for (int c = 0; c < 4; ++c)
#pragma unroll
      for (int i = 0; i < 4; ++i)
        mreg[c * 4 + i].v = *(const i32x8*)(
            Mb + (((size_t)(c * 32 + w * 4 + i) * 64 + lane) << 5));
  } else {
    const unsigned char* Mb = M8k + (size_t)b * NN * NN;
#pragma unroll
    for (int c = 0; c < 16; ++c)
#pragma unroll
      for (int i = 0; i < 4; ++i)
        mreg[c].l[i] = *(const long*)(
            Mb + (((size_t)(w * 64 + i * 16 + c)) << 9) + (size_t)lane * 8);
  }
  const float* ncbp = NCBg + (size_t)b * NSTEP * NN + t;
  const float* tcp = TCg + (size_t)b * NSTEP * NN + t;
  float ncb_c = ncbp[0];
  float tc_c = tcp[0];
  float ncb_n1 = 0.f, tc_n1 = 1.f;
  if (NSTEP > 1) { ncb_n1 = ncbp[NN]; tc_n1 = tcp[NN]; }
  float rlp = ncb_c;  // lp_0 == ncb_0
  lp8[0][t] = e4m3(rlp);
  __syncthreads();

  int pidx = -1;
  float pval = 0.f;
  for (int step = 0; step < NSTEP; ++step) {
    const int cb = step & 1;
    if (pidx >= 0) out[pidx] = pval;
    float ncb_n2 = 0.f, tc_n2 = 1.f;
    if (step + 2 < NSTEP) {
      ncb_n2 = ncbp[(size_t)(step + 2) * NN];
      tc_n2 = tcp[(size_t)(step + 2) * NN];
    }
    int sk_s = skill_s[step];
    f32x4 zero = {0.f, 0.f, 0.f, 0.f};
    f32x4 acc[4] = {zero, zero, zero, zero};
    if (use_mx) {
#pragma unroll
      for (int c = 0; c < 4; ++c) {
        i32x8 af = *(const i32x8*)(&lp8[cb][c * 128 + q * 32]);
#pragma unroll
        for (int i = 0; i < 4; ++i)
          acc[i] = __builtin_amdgcn_mfma_scale_f32_16x16x128_f8f6f4(
              af, mreg[c * 4 + i].v, acc[i], 0, 0, 0, 127, 0, 127);
      }
    } else {
#pragma unroll
      for (int c = 0; c < 16; ++c) {
        long af = *(const long*)(&lp8[cb][c * 32 + q * 8]);
#pragma unroll
        for (int i = 0; i < 4; ++i)
          acc[i] = __builtin_amdgcn_mfma_f32_16x16x32_fp8_fp8(af, mreg[c].l[i],
                                                              acc[i], 0, 0, 0);
      }
    }
    float spatial = ((q & 2) ? ((q & 1) ? acc[3][0] : acc[2][0])
                             : ((q & 1) ? acc[1][0] : acc[0][0])) * 0x1p-20f;
    float cur = 1.f / (1.f + __expf(-((ncb_c + tc_c * rlp) + spatial)));
    pidx = (t == sk_s) ? (step * BSZ + b) : -1;
    pval = cur;
    rlp = cur;
    lp8[cb ^ 1][t] = e4m3(cur);
    __syncthreads();
    ncb_c = ncb_n1; tc_c = tc_n1;
    ncb_n1 = ncb_n2; tc_n1 = tc_n2;
  }
  if (pidx >= 0) out[pidx] = pval;
}

// ---------------------------------------------------------------------------
// LEGACY scan — retained verbatim for low-workspace tiers.
// ---------------------------------------------------------------------------
__global__ __launch_bounds__(512, 2) void scan_kernel(
    const int* __restrict__ skills, const int* __restrict__ times,
    const float* __restrict__ labels, const float* __restrict__ emb,
    const float* __restrict__ ub0g, const float* __restrict__ uf0g,
    const float* __restrict__ w1g, const float* __restrict__ b1g,
    const float* __restrict__ w2g, const float* __restrict__ b2g,
    const float* __restrict__ wfg, const float* __restrict__ bfg,
    const float* __restrict__ wbg, const float* __restrict__ bbg,
    const unsigned char* __restrict__ M8k, const unsigned char* __restrict__ M8x,
    int allow_mx, const int* __restrict__ flag, float* __restrict__ out) {
  const int b = blockIdx.x;
  const int t = threadIdx.x;
  const int lane = t & 63, w = t >> 6, q = lane >> 4;

  __shared__ __align__(32) unsigned char lp8[NN];
  __shared__ float ub[DD], uf[DD];
  __shared__ float delta_s[NSTEP], label_s[NSTEP];
  __shared__ int skill_s[NSTEP];
  __shared__ float hp[16][33];
  __shared__ float w1t[DD * 5 * DD];
  __shared__ float w2t[DD * DD], wft[DD * DD], wbt[DD * DD];
  __shared__ float b1s[DD], b2s[DD], bfs[DD], bbs[DD];

  const int use_mx = allow_mx && (*flag);

  float nrec[DD], nsend[DD];
#pragma unroll
  for (int c = 0; c < DD; ++c) {
    nsend[c] = emb[(size_t)t * (2 * DD) + c];
    nrec[c] = emb[(size_t)t * (2 * DD) + DD + c];
  }
  for (int idx = t; idx < DD * DD * 5; idx += 512) {
    int o = idx / 160, rem = idx % 160;
    w1t[rem * 32 + o] = w1g[idx];
  }
  for (int idx = t; idx < DD * DD; idx += 512) {
    int o = idx >> 5, c = idx & 31;
    w2t[c * 32 + o] = w2g[idx];
    wft[c * 32 + o] = wfg[idx];
    wbt[c * 32 + o] = wbg[idx];
  }
  if (t < DD) {
    b1s[t] = b1g[t]; b2s[t] = b2g[t];
    bfs[t] = bfg[t]; bbs[t] = bbg[t];
    ub[t] = ub0g[b * DD + t];
    uf[t] = uf0g[b * DD + t];
  }
  for (int i = t; i < NSTEP; i += 512) {
    int dt_ = times[b * TTOT + i + 1] - times[b * TTOT + i];
    if (dt_ < 0) dt_ = -dt_;
    delta_s[i] = __logf((float)dt_ + 1e-6f) * 0.6213349345596119f;
    label_s[i] = labels[b * TTOT + i + 1];
    skill_s[i] = skills[b * TTOT + i + 1];
  }

  union MU { i32x8 v; long l[4]; };
  MU mreg[16];
  if (use_mx) {
    const unsigned char* Mb = M8x + (size_t)b * NN * NN;
#pragma unroll
    for (int c = 0; c < 4; ++c)
#pragma unroll
      for (int i = 0; i < 4; ++i)
        mreg[c * 4 + i].v = *(const i32x8*)(
            Mb + (((size_t)(c * 32 + w * 4 + i) * 64 + lane) << 5));
  } else {
    const unsigned char* Mb = M8k + (size_t)b * NN * NN;
#pragma unroll
    for (int c = 0; c < 16; ++c)
#pragma unroll
      for (int i = 0; i < 4; ++i)
        mreg[c].l[i] = *(const long*)(
            Mb + (((size_t)(w * 64 + i * 16 + c)) << 9) + (size_t)lane * 8);
  }
  __syncthreads();

  float rlp = 0.f, rnlf = 0.f;
#pragma unroll
  for (int c = 0; c < DD; ++c) {
    rlp += ub[c] * nrec[c];
    rnlf += uf[c] * nsend[c];
  }
  lp8[t] = e4m3(rlp);
  __syncthreads();

  for (int step = 0; step < NSTEP; ++step) {
    if (step && w == 0) {
      int o = lane & 31, half = lane >> 5;
      float part = 0.f;
#pragma unroll
      for (int s2 = 0; s2 < 8; ++s2) part += hp[half * 8 + s2][o];
      float h = b1s[o] + part + __shfl_xor(part, 32);
      h = fmaxf(h, 0.f);
      float up = 0.f;
#pragma unroll
      for (int cc = 0; cc < 16; ++cc) {
        float hv0 = rlane(h, cc), hv1 = rlane(h, 16 + cc);
        up += (half ? hv1 : hv0) * w2t[(half * 16 + cc) * 32 + o];
      }
      float uu = b2s[o] + up + __shfl_xor(up, 32);
      const float* wsel = half ? wbt : wft;
      float aac = half ? bbs[o] : bfs[o];
#pragma unroll
      for (int c = 0; c < DD; ++c) aac += rlane(uu, c) * wsel[c * 32 + o];
      float val = 1.f - 2.f / (1.f + __expf(2.f * aac));
      if (half) ub[o] = val;
      else uf[o] = val;
    }
    f32x4 zero = {0.f, 0.f, 0.f, 0.f};
    f32x4 acc[4] = {zero, zero, zero, zero};
    if (use_mx) {
#pragma unroll
      for (int c = 0; c < 4; ++c) {
        i32x8 af = *(const i32x8*)(&lp8[c * 128 + q * 32]);
#pragma unroll
        for (int i = 0; i < 4; ++i)
          acc[i] = __builtin_amdgcn_mfma_scale_f32_16x16x128_f8f6f4(
              af, mreg[c * 4 + i].v, acc[i], 0, 0, 0, 127, 0, 127);
      }
    } else {
#pragma unroll
      for (int c = 0; c < 16; ++c) {
        long af = *(const long*)(&lp8[c * 32 + q * 8]);
#pragma unroll
        for (int i = 0; i < 4; ++i)
          acc[i] = __builtin_amdgcn_mfma_f32_16x16x32_fp8_fp8(af, mreg[c].l[i],
                                                              acc[i], 0, 0, 0);
      }
    }
    float spatial = ((q & 2) ? ((q & 1) ? acc[3][0] : acc[2][0])
                             : ((q & 1) ? acc[1][0] : acc[0][0])) * 0x1p-20f;
    __syncthreads();

    float rub = ub[lane & 31], ruf = uf[lane & 31];
    float n0 = 0.f, n1 = 0.f, n2 = 0.f, n3 = 0.f;
    float l0 = 0.f, l1 = 0.f, l2 = 0.f, l3 = 0.f;
#pragma unroll
    for (int c = 0; c < 8; ++c) {
      n0 += rlane(rub, c) * nrec[c];
      n1 += rlane(rub, 8 + c) * nrec[8 + c];
      n2 += rlane(rub, 16 + c) * nrec[16 + c];
      n3 += rlane(rub, 24 + c) * nrec[24 + c];
      l0 += rlane(ruf, c) * nsend[c];
      l1 += rlane(ruf, 8 + c) * nsend[8 + c];
      l2 += rlane(ruf, 16 + c) * nsend[16 + c];
      l3 += rlane(ruf, 24 + c) * nsend[24 + c];
    }
    float ncb = (n0 + n1) + (n2 + n3);
    float nlfn = (l0 + l1) + (l2 + l3);
    float e = __expf(-delta_s[step] * 0.1f * rnlf) * rlp;
    float cur = 1.f / (1.f + __expf(-(ncb + e + spatial)));

    {
      int o = t & 31, s = t >> 5;
      float lab = label_s[step];
      int sk = skill_s[step];
      float hpart = 0.f;
#pragma unroll
      for (int cc = 0; cc < 2; ++cc) {
        int c = (s << 1) + cc;
        const float* wrow = &w1t[(c * 5) * 32 + o];
        float rs = emb[(size_t)sk * (2 * DD) + c];
        float rr = emb[(size_t)sk * (2 * DD) + DD + c];
        hpart += ub[c] * wrow[0] + uf[c] * wrow[32] + lab * wrow[64] +
                 rr * wrow[96] + rs * wrow[128];
      }
      hp[s][o] = hpart;
    }

    rlp = cur;
    rnlf = nlfn;
    lp8[t] = e4m3(cur);
    if (t == skill_s[step]) out[step * BSZ + b] = cur;
    __syncthreads();
  }
}

extern "C" void kernel_launch(void* const* d_in, const int* in_sizes, int n_in,
                              void* d_out, int out_size, void* d_ws, size_t ws_size,
                              hipStream_t stream) {
  (void)in_sizes; (void)n_in; (void)out_size;
  const int* skills = (const int*)d_in[0];
  const int* times = (const int*)d_in[1];
  const float* labels = (const float*)d_in[2];
  const float* adj = (const float*)d_in[3];
  const float* emb = (const float*)d_in[4];
  const float* ub0 = (const float*)d_in[5];
  const float* uf0 = (const float*)d_in[6];
  const float* w1 = (const float*)d_in[7];
  const float* b1 = (const float*)d_in[8];
  const float* w2 = (const float*)d_in[9];
  const float* b2 = (const float*)d_in[10];
  const float* wf = (const float*)d_in[11];
  const float* bf = (const float*)d_in[12];
  const float* wb = (const float*)d_in[13];
  const float* bb = (const float*)d_in[14];

  const size_t mat = (size_t)BSZ * NN * NN;                        // 16,777,216
  const size_t ncb_sz = (size_t)BSZ * NSTEP * NN * sizeof(float);  // 26,083,328
  const size_t ub_sz = (size_t)BSZ * NSTEP * DD * sizeof(float);   //  1,630,208
  char* base = (char*)d_ws;
  unsigned char *M8k, *M8x;
  unsigned short* A2;
  char* ovl = nullptr;  // scratch region (ex-A1T/A2 space) -> NCB/TC/UB/UF
  int* flag;
  int use_fast, allow_mx;
  if (ws_size >= 6 * mat + 4) {          // fast gemms + MX
    use_fast = 1; allow_mx = 1;
    M8k = (unsigned char*)base; M8x = M8k + mat;
    A2 = (unsigned short*)(base + 2 * mat);
    flag = (int*)(base + 6 * mat);
    ovl = base + 2 * mat;                // 67.1 MB >= 55.4 MB needed
  } else if (ws_size >= 5 * mat + 4) {   // fast gemms, no MX
    use_fast = 1; allow_mx = 0;
    M8k = (unsigned char*)base; M8x = M8k;
    A2 = (unsigned short*)(base + mat);
    flag = (int*)(base + 5 * mat);
    ovl = base + mat;
  } else if (ws_size >= 4 * mat + 4) {   // slow gemms + MX (legacy scan)
    use_fast = 0; allow_mx = 1;
    M8k = (unsigned char*)base; M8x = M8k + mat;
    A2 = (unsigned short*)(base + 2 * mat);
    flag = (int*)(base + 4 * mat);
  } else {                               // slow, no MX (legacy scan)
    use_fast = 0; allow_mx = 0;
    M8k = (unsigned char*)base; M8x = M8k;
    A2 = (unsigned short*)(base + mat);
    flag = (int*)(base + 3 * mat);
  }

  dim3 gb(256);
  if (use_fast) {
    dim3 gf(4, 4, BSZ);   // staged gemms: 128-tiles, batch-adjacent
    gemm_a2_fast<<<gf, gb, 0, stream>>>(adj, A2);
    gemm_m_fast<<<gf, gb, 0, stream>>>(adj, A2, M8k, M8x, allow_mx);
    // NOTE: NCB overlays A2's region — safe because gemm_m has consumed A2
    // before precomp writes NCB (stream order), and UB/UF sit past NCB+TC.
    float* NCB = (float*)ovl;
    float* TC = (float*)(ovl + ncb_sz);
    float* UB = (float*)(ovl + 2 * ncb_sz);
    float* UF = (float*)(ovl + 2 * ncb_sz + ub_sz);
    traj2_kernel<<<dim3(BSZ), dim3(64), 0, stream>>>(
        skills, labels, emb, ub0, uf0, w1, b1, w2, b2, wf, bf, wb, bb, UB, UF);
    precomp_kernel<<<dim3(BSZ, 25), dim3(512), 0, stream>>>(times, emb, UB, UF,
                                                            NCB, TC);
    probe_kernel<<<dim3(1), dim3(64), 0, stream>>>(flag);
    scan_fast<<<dim3(BSZ), dim3(512), 0, stream>>>(skills, NCB, TC, M8k, M8x,
                                                   allow_mx, flag, (float*)d_out);
  } else {
    dim3 gg(BSZ, 8, 8);
    gemm_a2_slow<<<gg, gb, 0, stream>>>(adj, A2);
    gemm_m_slow<<<gg, gb, 0, stream>>>(adj, A2, M8k, M8x, allow_mx);
    probe_kernel<<<dim3(1), dim3(64), 0, stream>>>(flag);
    scan_kernel<<<dim3(BSZ), dim3(512), 0, stream>>>(
        skills, times, labels, emb, ub0, uf0, w1, b1, w2, b2, wf, bf, wb, bb,
        M8k, M8x, allow_mx, flag, (float*)d_out);
  }
}